// Round 4
// baseline (1082.581 us; speedup 1.0000x reference)
//
#include <hip/hip_runtime.h>
#include <hip/hip_fp16.h>
#include <cstdint>

using f16 = _Float16;
typedef __attribute__((ext_vector_type(8))) _Float16 f16x8;
typedef __attribute__((ext_vector_type(4))) float f32x4;

#define MFMA16(a, b, c) __builtin_amdgcn_mfma_f32_16x16x32_f16((a), (b), (c), 0, 0, 0)

__device__ __forceinline__ f16x8 ldfrag(const f16* p) { return *(const f16x8*)p; }

// Problem constants: B=8, T=1024, K=128, H=8 -> M = B*H = 64 scrambled batches.
static const int64_t NX = 1048576;   // x elements: 8*1024*128
static const int64_t NW = 655360;    // Wq/Wk elements: 1024*128*5
static const int64_t NV = 131072;    // Wv / Wu elements: 1024*128

// ---------------- K0: split-convert/repack weights and x to fp16 hi/lo -----
__global__ __launch_bounds__(256) void k0_prep(
    const float* __restrict__ x, const float* __restrict__ Wq,
    const float* __restrict__ Wk, const float* __restrict__ Wv,
    const float* __restrict__ Wu,
    f16* __restrict__ xh, f16* __restrict__ xl,
    f16* __restrict__ Wqh, f16* __restrict__ Wql,
    f16* __restrict__ Wkh, f16* __restrict__ Wkl,
    f16* __restrict__ Wvb, f16* __restrict__ Wub) {
  int64_t i = (int64_t)blockIdx.x * 256 + threadIdx.x;  // grid sized exactly
  if (i < NX) {
    const float v = x[i];
    const f16 h = (f16)v;
    xh[i] = h; xl[i] = (f16)(v - (float)h);
  } else if (i < NX + NW) {
    int64_t d = i - NX;
    int j = (int)(d >> 17);
    int rem = (int)(d & 131071);
    int o = rem >> 7, c = rem & 127;
    const float v = Wq[(int64_t)(o * 128 + c) * 5 + j];   // layout [j][o][c]
    const f16 h = (f16)v;
    Wqh[d] = h; Wql[d] = (f16)(v - (float)h);
  } else if (i < NX + 2 * NW) {
    int64_t d = i - NX - NW;
    int j = (int)(d >> 17);
    int rem = (int)(d & 131071);
    int o = rem >> 7, c = rem & 127;
    const float v = Wk[(int64_t)(o * 128 + c) * 5 + j];
    const f16 h = (f16)v;
    Wkh[d] = h; Wkl[d] = (f16)(v - (float)h);
  } else if (i < NX + 2 * NW + NV) {
    int64_t d = i - NX - 2 * NW;
    Wvb[d] = (f16)Wv[d];                                // [o][c]
  } else {
    int64_t d = i - NX - 2 * NW - NV;
    Wub[d] = (f16)Wu[d];                                // [c][o]
  }
}

// ---------------- K1: causal convs (split-f16) + LDS-staged coalesced out --
// blockIdx = (row-tile of 32, channel-half of 512, Q-or-K). 256 thr = 4 waves,
// each wave owns 128 channels. Q-blocks also compute V (pointwise).
// q3/k3: [m=64][t2=1024][kc=128] hi+lo fp16 (scaled); v3T: [m][kc][t2] fp16.
#define STAGE_QK(DST, VALEXPR)                                          \
  {                                                                     \
    __syncthreads();                                                    \
    _Pragma("unroll")                                                   \
    for (int nt = 0; nt < 8; ++nt) {                                    \
      const int o = o0 + nt * 16 + lo;                                  \
      const int kcl = (o >> 3) & 63, hh = o & 7;                        \
      _Pragma("unroll")                                                 \
      for (int rt = 0; rt < 2; ++rt) {                                  \
        _Pragma("unroll")                                               \
        for (int r = 0; r < 4; ++r) {                                   \
          const int t2l = (rt * 16 + quad * 4 + r) * 8 + hh;            \
          lds[t2l * 72 + kcl] = (VALEXPR);                              \
        }                                                               \
      }                                                                 \
    }                                                                   \
    __syncthreads();                                                    \
    _Pragma("unroll")                                                   \
    for (int p = 0; p < 8; ++p) {                                       \
      const int idx = p * 256 + tid;                                    \
      const int a = idx >> 3, c8 = (idx & 7) * 8;                       \
      *(f16x8*)(DST + ((int64_t)m * 1024 + t2b + a) * 128 +             \
                half * 64 + c8) = *(const f16x8*)&lds[a * 72 + c8];     \
    }                                                                   \
  }

__global__ __launch_bounds__(256) void k1_conv(
    const f16* __restrict__ xh, const f16* __restrict__ xl,
    const f16* __restrict__ Wqh, const f16* __restrict__ Wql,
    const f16* __restrict__ Wkh, const f16* __restrict__ Wkl,
    const f16* __restrict__ Wvb,
    const float* __restrict__ bq, const float* __restrict__ bk,
    const float* __restrict__ bv,
    f16* __restrict__ q3h, f16* __restrict__ q3l,
    f16* __restrict__ k3h, f16* __restrict__ k3l,
    f16* __restrict__ v3T) {
  __shared__ f16 lds[18432];  // max(256*72, 64*264) elems = 36.9 KB
  const int tid = threadIdx.x;
  const int w = tid >> 6, lane = tid & 63;
  const int quad = lane >> 4, lo = lane & 15;
  const int r0 = blockIdx.x * 32;     // rows r0..r0+31 (same b, same m)
  const int bb = r0 >> 10;
  const int m  = r0 >> 7;
  const int t2b = (r0 & 127) * 8;
  const int half = blockIdx.y;        // which 512-channel half
  const int isK = blockIdx.z;         // 0 = Q (+V), 1 = K
  const int o0 = half * 512 + w * 128;

  const f16* Wh = isK ? Wkh : Wqh;
  const f16* Wl = isK ? Wkl : Wql;
  const float* bias = isK ? bk : bq;

  // ---- V pass (Q-blocks only): 1 tap, hi only ----
  if (!isK) {
    f32x4 av[2][8];
#pragma unroll
    for (int rt = 0; rt < 2; ++rt)
#pragma unroll
      for (int i = 0; i < 8; ++i)
#pragma unroll
        for (int r = 0; r < 4; ++r) av[rt][i][r] = 0.f;

#pragma unroll
    for (int kk = 0; kk < 4; ++kk) {
      const int koff = kk * 32 + quad * 8;
      f16x8 ah[2];
#pragma unroll
      for (int rt = 0; rt < 2; ++rt) {
        const int tt = (r0 + rt * 16 + lo) & 1023;
        ah[rt] = ldfrag(xh + ((int64_t)(bb * 1024 + tt)) * 128 + koff);
      }
#pragma unroll
      for (int nt = 0; nt < 8; ++nt) {
        const int n = o0 + nt * 16 + lo;
        f16x8 bv8 = ldfrag(Wvb + (int64_t)n * 128 + koff);
        av[0][nt] = MFMA16(ah[0], bv8, av[0][nt]);
        av[1][nt] = MFMA16(ah[1], bv8, av[1][nt]);
      }
    }
    // stage v3T via LDS [kcl][t2l] (stride 264), coalesced out
#pragma unroll
    for (int nt = 0; nt < 8; ++nt) {
      const int o = o0 + nt * 16 + lo;
      const float vbv = bv[o];
      const int kcl = (o >> 3) & 63, hh = o & 7;
#pragma unroll
      for (int rt = 0; rt < 2; ++rt)
#pragma unroll
        for (int r = 0; r < 4; ++r) {
          const int t2l = (rt * 16 + quad * 4 + r) * 8 + hh;
          lds[kcl * 264 + t2l] = (f16)(av[rt][nt][r] + vbv);
        }
    }
    __syncthreads();
#pragma unroll
    for (int p = 0; p < 8; ++p) {
      const int idx = p * 256 + tid;
      const int kcl = idx >> 5, t8 = (idx & 31) * 8;
      *(f16x8*)(v3T + ((int64_t)m * 128 + half * 64 + kcl) * 1024 + t2b + t8) =
          *(const f16x8*)&lds[kcl * 264 + t8];
    }
  }

  // ---- Q or K main loop: 5 taps, split-f16 (3 MFMAs per tap) ----
  f32x4 aq[2][8];
#pragma unroll
  for (int rt = 0; rt < 2; ++rt)
#pragma unroll
    for (int i = 0; i < 8; ++i)
#pragma unroll
      for (int r = 0; r < 4; ++r) aq[rt][i][r] = 0.f;

#pragma unroll
  for (int j = 0; j < 5; ++j) {
    bool ok[2]; int64_t xoff[2];
#pragma unroll
    for (int rt = 0; rt < 2; ++rt) {
      const int tt = (r0 + rt * 16 + lo) & 1023;
      const int tp = tt + j - 4;            // causal left-pad 4
      ok[rt] = (tp >= 0);
      xoff[rt] = ((int64_t)(bb * 1024 + (ok[rt] ? tp : 0))) * 128;
    }
#pragma unroll
    for (int kk = 0; kk < 4; ++kk) {
      const int koff = kk * 32 + quad * 8;
      f16x8 ah[2], al[2];
#pragma unroll
      for (int rt = 0; rt < 2; ++rt) {
        ah[rt] = ldfrag(xh + xoff[rt] + koff);
        al[rt] = ldfrag(xl + xoff[rt] + koff);
        if (!ok[rt]) {
#pragma unroll
          for (int e = 0; e < 8; ++e) { ah[rt][e] = (f16)0; al[rt][e] = (f16)0; }
        }
      }
#pragma unroll
      for (int nt = 0; nt < 8; ++nt) {
        const int n = o0 + nt * 16 + lo;
        const int64_t wi = (int64_t)j * 131072 + (int64_t)n * 128 + koff;
        f16x8 bh = ldfrag(Wh + wi);
        f16x8 bl = ldfrag(Wl + wi);
#pragma unroll
        for (int rt = 0; rt < 2; ++rt) {
          aq[rt][nt] = MFMA16(ah[rt], bh, aq[rt][nt]);
          aq[rt][nt] = MFMA16(ah[rt], bl, aq[rt][nt]);
          aq[rt][nt] = MFMA16(al[rt], bh, aq[rt][nt]);
        }
      }
    }
  }

  const float SC = 0.29730177875068026f;  // 128^-0.25
#pragma unroll
  for (int nt = 0; nt < 8; ++nt) {
    const int o = o0 + nt * 16 + lo;
    const float vb = bias[o];
#pragma unroll
    for (int rt = 0; rt < 2; ++rt)
#pragma unroll
      for (int r = 0; r < 4; ++r) aq[rt][nt][r] = (aq[rt][nt][r] + vb) * SC;
  }

  if (!isK) {
    STAGE_QK(q3h, (f16)aq[rt][nt][r])
    STAGE_QK(q3l, (f16)(aq[rt][nt][r] - (float)(f16)aq[rt][nt][r]))
  } else {
    STAGE_QK(k3h, (f16)aq[rt][nt][r])
    STAGE_QK(k3l, (f16)(aq[rt][nt][r] - (float)(f16)aq[rt][nt][r]))
  }
}

// ---------------- K234: fused scores + top-64/softmax + PV -----------------
// One block = 16 t2-rows x full 1024 cols of one m. S kept in LDS fp32
// (stride 1028 keeps 16B alignment, <=2-way banks on hot paths). Phase 2
// writes probabilities back in place; phase 3 builds f16 A-frags from LDS.
__global__ __launch_bounds__(256) void k234_attn(
    const f16* __restrict__ q3h, const f16* __restrict__ q3l,
    const f16* __restrict__ k3h, const f16* __restrict__ k3l,
    const f16* __restrict__ v3T, f16* __restrict__ A) {
  __shared__ float S[16 * 1028];  // 65,792 B
  const int tid = threadIdx.x;
  const int w = tid >> 6, lane = tid & 63;
  const int quad = lane >> 4, lo = lane & 15;
  const int m = blockIdx.y;
  const int r0 = blockIdx.x * 16;  // t2-row tile

  // ---- phase 1: S = Q3 @ K3^T (split-f16, fp32 acc) ----
  {
    f32x4 acc[16];
#pragma unroll
    for (int i = 0; i < 16; ++i)
#pragma unroll
      for (int r = 0; r < 4; ++r) acc[i][r] = 0.f;

    const int64_t qoff = ((int64_t)m * 1024 + r0 + lo) * 128;
#pragma unroll
    for (int kk = 0; kk < 4; ++kk) {
      const int koff = kk * 32 + quad * 8;
      f16x8 ah = ldfrag(q3h + qoff + koff);
      f16x8 al = ldfrag(q3l + qoff + koff);
#pragma unroll
      for (int nt = 0; nt < 16; ++nt) {
        const int col = w * 256 + nt * 16 + lo;
        const int64_t bi = ((int64_t)m * 1024 + col) * 128 + koff;
        f16x8 bh = ldfrag(k3h + bi);
        f16x8 bl = ldfrag(k3l + bi);
        acc[nt] = MFMA16(ah, bh, acc[nt]);
        acc[nt] = MFMA16(ah, bl, acc[nt]);
        acc[nt] = MFMA16(al, bh, acc[nt]);
      }
    }
#pragma unroll
    for (int nt = 0; nt < 16; ++nt)
#pragma unroll
      for (int r = 0; r < 4; ++r)
        S[(quad * 4 + r) * 1028 + w * 256 + nt * 16 + lo] = acc[nt][r];
  }
  __syncthreads();

  // ---- phase 2: exact fp32 top-64 + rowmin + causal + softmax, in place ----
  for (int rr = 0; rr < 4; ++rr) {
    const int row = w * 4 + rr;
    const int t2 = r0 + row;
    float* srow = S + row * 1028;

    float v[16];
    unsigned key[16];
    float mn = 1e30f;
    unsigned kmax = 0, kmin = 0xFFFFFFFFu;
#pragma unroll
    for (int i = 0; i < 16; ++i) {
      const float f = srow[i * 64 + lane];
      v[i] = f;
      const unsigned u = __builtin_bit_cast(unsigned, f);
      const unsigned k = (u & 0x80000000u) ? ~u : (u | 0x80000000u);
      key[i] = k;
      mn = fminf(mn, f);
      kmax = max(kmax, k);
      kmin = min(kmin, k);
    }
    for (int off = 32; off; off >>= 1) {
      mn = fminf(mn, __shfl_xor(mn, off));
      kmax = max(kmax, (unsigned)__shfl_xor((int)kmax, off));
      kmin = min(kmin, (unsigned)__shfl_xor((int)kmin, off));
    }

    unsigned long long blo = kmin, bhi = kmax;
    while (blo < bhi) {
      const unsigned long long mid = blo + ((bhi - blo + 1) >> 1);
      int cnt = 0;
#pragma unroll
      for (int i = 0; i < 16; ++i) cnt += (key[i] >= (unsigned)mid) ? 1 : 0;
      for (int off = 32; off; off >>= 1) cnt += __shfl_xor(cnt, off);
      if (cnt >= 64) blo = mid; else bhi = mid - 1;
    }
    const unsigned kth = (unsigned)blo;

    float wv[16];
    float mx = -1e30f;
#pragma unroll
    for (int i = 0; i < 16; ++i) {
      const int s = i * 64 + lane;
      const float ww = (key[i] >= kth) ? v[i] : mn;
      wv[i] = ww;
      if (s <= t2) mx = fmaxf(mx, ww);
    }
    for (int off = 32; off; off >>= 1) mx = fmaxf(mx, __shfl_xor(mx, off));

    float ev[16];
    float sum = 0.f;
#pragma unroll
    for (int i = 0; i < 16; ++i) {
      const int s = i * 64 + lane;
      const float x = (s <= t2) ? expf(wv[i] - mx) : 0.f;
      ev[i] = x;
      sum += x;
    }
    for (int off = 32; off; off >>= 1) sum += __shfl_xor(sum, off);
    const float inv = 1.0f / sum;
#pragma unroll
    for (int i = 0; i < 16; ++i) srow[i * 64 + lane] = ev[i] * inv;
  }
  __syncthreads();

  // ---- phase 3: A-tile = P @ V (K = 1024), A-frags from LDS f32 -> f16 ----
  {
    f32x4 oacc[2];
#pragma unroll
    for (int nt = 0; nt < 2; ++nt)
#pragma unroll
      for (int r = 0; r < 4; ++r) oacc[nt][r] = 0.f;

    for (int ks = 0; ks < 32; ++ks) {
      const int k0 = ks * 32 + quad * 8;
      const float* sr = S + lo * 1028 + k0;
      f16x8 a;
#pragma unroll
      for (int e = 0; e < 8; ++e) a[e] = (f16)sr[e];
#pragma unroll
      for (int nt = 0; nt < 2; ++nt) {
        const int kc = w * 32 + nt * 16 + lo;
        f16x8 fb = ldfrag(v3T + ((int64_t)m * 128 + kc) * 1024 + k0);
        oacc[nt] = MFMA16(a, fb, oacc[nt]);
      }
    }
#pragma unroll
    for (int nt = 0; nt < 2; ++nt)
#pragma unroll
      for (int r = 0; r < 4; ++r) {
        const int row = r0 + quad * 4 + r, col = w * 32 + nt * 16 + lo;
        A[((int64_t)m * 1024 + row) * 128 + col] = (f16)oacc[nt][r];
      }
  }
}

// ---------------- K5: gather + output projection + bias --------------------
__global__ __launch_bounds__(256) void k5_proj(
    const f16* __restrict__ A, const f16* __restrict__ Wub,
    const float* __restrict__ bu, float* __restrict__ out) {
  const int w = threadIdx.x >> 6, lane = threadIdx.x & 63;
  const int quad = lane >> 4, lo = lane & 15;
  const int r0 = blockIdx.x * 64 + w * 16;  // row in [0, 8192) = b*1024 + t2
  const int r = r0 + lo;
  const int bI = r >> 10, t2 = r & 1023;

  f32x4 acc[8];
#pragma unroll
  for (int i = 0; i < 8; ++i)
#pragma unroll
    for (int rr = 0; rr < 4; ++rr) acc[i][rr] = 0.f;

  for (int kk = 0; kk < 32; ++kk) {
    const int o = kk * 32 + quad * 8;  // feature index 0..1023
    const int j = o >> 7, kc = o & 127;
    f16x8 a = ldfrag(A + (((int64_t)(bI * 8 + j) * 1024 + t2) * 128 + kc));
#pragma unroll
    for (int nt = 0; nt < 8; ++nt) {
      f16x8 fb = ldfrag(Wub + (int64_t)(nt * 16 + lo) * 1024 + o);
      acc[nt] = MFMA16(a, fb, acc[nt]);
    }
  }
#pragma unroll
  for (int nt = 0; nt < 8; ++nt) {
    const int col = nt * 16 + lo;
    const float bias = bu[col];
#pragma unroll
    for (int rr = 0; rr < 4; ++rr) {
      const int row = r0 + quad * 4 + rr;
      out[(int64_t)row * 128 + col] = acc[nt][rr] + bias;
    }
  }
}

// ---------------- launcher --------------------------------------------------
extern "C" void kernel_launch(void* const* d_in, const int* in_sizes, int n_in,
                              void* d_out, int out_size, void* d_ws, size_t ws_size,
                              hipStream_t stream) {
  const float* x  = (const float*)d_in[0];
  const float* Wq = (const float*)d_in[1];
  const float* bq = (const float*)d_in[2];
  const float* Wk = (const float*)d_in[3];
  const float* bk = (const float*)d_in[4];
  const float* Wv = (const float*)d_in[5];
  const float* bv = (const float*)d_in[6];
  const float* Wu = (const float*)d_in[7];
  const float* bu = (const float*)d_in[8];
  float* out = (float*)d_out;

  char* ws = (char*)d_ws;
  f16* xh  = (f16*)ws;  ws += 2097152;
  f16* xl  = (f16*)ws;  ws += 2097152;
  f16* Wqh = (f16*)ws;  ws += 1310720;
  f16* Wql = (f16*)ws;  ws += 1310720;
  f16* Wkh = (f16*)ws;  ws += 1310720;
  f16* Wkl = (f16*)ws;  ws += 1310720;
  f16* Wvb = (f16*)ws;  ws += 262144;
  f16* Wub = (f16*)ws;  ws += 262144;
  f16* q3h = (f16*)ws;  ws += 16777216;           // 64*1024*128 fp16
  f16* q3l = (f16*)ws;  ws += 16777216;
  f16* k3h = (f16*)ws;  ws += 16777216;
  f16* k3l = (f16*)ws;  ws += 16777216;
  f16* v3T = (f16*)ws;  ws += 16777216;
  f16* A   = (f16*)ws;  ws += 16777216;           // total ~105.5 MB

  // K0: repack (exactly 2621440 threads = 10240 * 256)
  k0_prep<<<10240, 256, 0, stream>>>(x, Wq, Wk, Wv, Wu,
                                     xh, xl, Wqh, Wql, Wkh, Wkl, Wvb, Wub);

  // K1: convs + scramble; (row-tile, ch-half, Q/K) blocks of 4 waves
  k1_conv<<<dim3(256, 2, 2), 256, 0, stream>>>(xh, xl, Wqh, Wql, Wkh, Wkl, Wvb,
                                               bq, bk, bv, q3h, q3l, k3h, k3l,
                                               v3T);

  // K234: fused scores + selection/softmax + PV, one launch
  k234_attn<<<dim3(64, 64), 256, 0, stream>>>(q3h, q3l, k3h, k3l, v3T, A);

  // K5: projection (8192 rows / 64 per block)
  k5_proj<<<128, 256, 0, stream>>>(A, Wub, bu, out);

  (void)in_sizes; (void)n_in; (void)out_size; (void)ws_size;
}

// Round 5
// 989.755 us; speedup vs baseline: 1.0938x; 1.0938x over previous
//
#include <hip/hip_runtime.h>
#include <hip/hip_fp16.h>
#include <cstdint>

using f16 = _Float16;
typedef __attribute__((ext_vector_type(8))) _Float16 f16x8;
typedef __attribute__((ext_vector_type(4))) float f32x4;

#define MFMA16(a, b, c) __builtin_amdgcn_mfma_f32_16x16x32_f16((a), (b), (c), 0, 0, 0)

__device__ __forceinline__ f16x8 ldfrag(const f16* p) { return *(const f16x8*)p; }

// Problem constants: B=8, T=1024, K=128, H=8 -> M = B*H = 64 scrambled batches.
static const int64_t NX = 1048576;   // x elements: 8*1024*128
static const int64_t NW = 655360;    // Wq/Wk elements: 1024*128*5
static const int64_t NV = 131072;    // Wv / Wu elements: 1024*128

// ---------------- K0: split-convert/repack weights and x to fp16 hi/lo -----
__global__ __launch_bounds__(256) void k0_prep(
    const float* __restrict__ x, const float* __restrict__ Wq,
    const float* __restrict__ Wk, const float* __restrict__ Wv,
    const float* __restrict__ Wu,
    f16* __restrict__ xh, f16* __restrict__ xl,
    f16* __restrict__ Wqh, f16* __restrict__ Wql,
    f16* __restrict__ Wkh, f16* __restrict__ Wkl,
    f16* __restrict__ Wvb, f16* __restrict__ Wub) {
  int64_t i = (int64_t)blockIdx.x * 256 + threadIdx.x;  // grid sized exactly
  if (i < NX) {
    const float v = x[i];
    const f16 h = (f16)v;
    xh[i] = h; xl[i] = (f16)(v - (float)h);
  } else if (i < NX + NW) {
    int64_t d = i - NX;
    int j = (int)(d >> 17);
    int rem = (int)(d & 131071);
    int o = rem >> 7, c = rem & 127;
    const float v = Wq[(int64_t)(o * 128 + c) * 5 + j];   // layout [j][o][c]
    const f16 h = (f16)v;
    Wqh[d] = h; Wql[d] = (f16)(v - (float)h);
  } else if (i < NX + 2 * NW) {
    int64_t d = i - NX - NW;
    int j = (int)(d >> 17);
    int rem = (int)(d & 131071);
    int o = rem >> 7, c = rem & 127;
    const float v = Wk[(int64_t)(o * 128 + c) * 5 + j];
    const f16 h = (f16)v;
    Wkh[d] = h; Wkl[d] = (f16)(v - (float)h);
  } else if (i < NX + 2 * NW + NV) {
    int64_t d = i - NX - 2 * NW;
    Wvb[d] = (f16)Wv[d];                                // [o][c]
  } else {
    int64_t d = i - NX - 2 * NW - NV;
    Wub[d] = (f16)Wu[d];                                // [c][o]
  }
}

// ---------------- K1: causal convs (split-f16) + LDS-staged coalesced out --
// blockIdx = (row-tile of 32, channel-half of 512, Q-or-K). 256 thr = 4 waves,
// each wave owns 128 channels. Q-blocks also compute V (pointwise).
// q3/k3: [m=64][t2=1024][kc=128] hi+lo fp16 (scaled); v3T: [m][kc][t2] fp16.
#define STAGE_QK(DST, VALEXPR)                                          \
  {                                                                     \
    __syncthreads();                                                    \
    _Pragma("unroll")                                                   \
    for (int nt = 0; nt < 8; ++nt) {                                    \
      const int o = o0 + nt * 16 + lo;                                  \
      const int kcl = (o >> 3) & 63, hh = o & 7;                        \
      _Pragma("unroll")                                                 \
      for (int rt = 0; rt < 2; ++rt) {                                  \
        _Pragma("unroll")                                               \
        for (int r = 0; r < 4; ++r) {                                   \
          const int t2l = (rt * 16 + quad * 4 + r) * 8 + hh;            \
          lds[t2l * 72 + kcl] = (VALEXPR);                              \
        }                                                               \
      }                                                                 \
    }                                                                   \
    __syncthreads();                                                    \
    _Pragma("unroll")                                                   \
    for (int p = 0; p < 8; ++p) {                                       \
      const int idx = p * 256 + tid;                                    \
      const int a = idx >> 3, c8 = (idx & 7) * 8;                       \
      *(f16x8*)(DST + ((int64_t)m * 1024 + t2b + a) * 128 +             \
                half * 64 + c8) = *(const f16x8*)&lds[a * 72 + c8];     \
    }                                                                   \
  }

__global__ __launch_bounds__(256) void k1_conv(
    const f16* __restrict__ xh, const f16* __restrict__ xl,
    const f16* __restrict__ Wqh, const f16* __restrict__ Wql,
    const f16* __restrict__ Wkh, const f16* __restrict__ Wkl,
    const f16* __restrict__ Wvb,
    const float* __restrict__ bq, const float* __restrict__ bk,
    const float* __restrict__ bv,
    f16* __restrict__ q3h, f16* __restrict__ q3l,
    f16* __restrict__ k3h, f16* __restrict__ k3l,
    f16* __restrict__ v3T) {
  __shared__ f16 lds[18432];  // max(256*72, 64*264) elems = 36.9 KB
  const int tid = threadIdx.x;
  const int w = tid >> 6, lane = tid & 63;
  const int quad = lane >> 4, lo = lane & 15;
  const int r0 = blockIdx.x * 32;     // rows r0..r0+31 (same b, same m)
  const int bb = r0 >> 10;
  const int m  = r0 >> 7;
  const int t2b = (r0 & 127) * 8;
  const int half = blockIdx.y;        // which 512-channel half
  const int isK = blockIdx.z;         // 0 = Q (+V), 1 = K
  const int o0 = half * 512 + w * 128;

  const f16* Wh = isK ? Wkh : Wqh;
  const f16* Wl = isK ? Wkl : Wql;
  const float* bias = isK ? bk : bq;

  // ---- V pass (Q-blocks only): 1 tap, hi only ----
  if (!isK) {
    f32x4 av[2][8];
#pragma unroll
    for (int rt = 0; rt < 2; ++rt)
#pragma unroll
      for (int i = 0; i < 8; ++i)
#pragma unroll
        for (int r = 0; r < 4; ++r) av[rt][i][r] = 0.f;

#pragma unroll
    for (int kk = 0; kk < 4; ++kk) {
      const int koff = kk * 32 + quad * 8;
      f16x8 ah[2];
#pragma unroll
      for (int rt = 0; rt < 2; ++rt) {
        const int tt = (r0 + rt * 16 + lo) & 1023;
        ah[rt] = ldfrag(xh + ((int64_t)(bb * 1024 + tt)) * 128 + koff);
      }
#pragma unroll
      for (int nt = 0; nt < 8; ++nt) {
        const int n = o0 + nt * 16 + lo;
        f16x8 bv8 = ldfrag(Wvb + (int64_t)n * 128 + koff);
        av[0][nt] = MFMA16(ah[0], bv8, av[0][nt]);
        av[1][nt] = MFMA16(ah[1], bv8, av[1][nt]);
      }
    }
    // stage v3T via LDS [kcl][t2l] (stride 264), coalesced out
#pragma unroll
    for (int nt = 0; nt < 8; ++nt) {
      const int o = o0 + nt * 16 + lo;
      const float vbv = bv[o];
      const int kcl = (o >> 3) & 63, hh = o & 7;
#pragma unroll
      for (int rt = 0; rt < 2; ++rt)
#pragma unroll
        for (int r = 0; r < 4; ++r) {
          const int t2l = (rt * 16 + quad * 4 + r) * 8 + hh;
          lds[kcl * 264 + t2l] = (f16)(av[rt][nt][r] + vbv);
        }
    }
    __syncthreads();
#pragma unroll
    for (int p = 0; p < 8; ++p) {
      const int idx = p * 256 + tid;
      const int kcl = idx >> 5, t8 = (idx & 31) * 8;
      *(f16x8*)(v3T + ((int64_t)m * 128 + half * 64 + kcl) * 1024 + t2b + t8) =
          *(const f16x8*)&lds[kcl * 264 + t8];
    }
  }

  // ---- Q or K main loop: 5 taps, split-f16 (3 MFMAs per tap) ----
  f32x4 aq[2][8];
#pragma unroll
  for (int rt = 0; rt < 2; ++rt)
#pragma unroll
    for (int i = 0; i < 8; ++i)
#pragma unroll
      for (int r = 0; r < 4; ++r) aq[rt][i][r] = 0.f;

#pragma unroll
  for (int j = 0; j < 5; ++j) {
    bool ok[2]; int64_t xoff[2];
#pragma unroll
    for (int rt = 0; rt < 2; ++rt) {
      const int tt = (r0 + rt * 16 + lo) & 1023;
      const int tp = tt + j - 4;            // causal left-pad 4
      ok[rt] = (tp >= 0);
      xoff[rt] = ((int64_t)(bb * 1024 + (ok[rt] ? tp : 0))) * 128;
    }
#pragma unroll
    for (int kk = 0; kk < 4; ++kk) {
      const int koff = kk * 32 + quad * 8;
      f16x8 ah[2], al[2];
#pragma unroll
      for (int rt = 0; rt < 2; ++rt) {
        ah[rt] = ldfrag(xh + xoff[rt] + koff);
        al[rt] = ldfrag(xl + xoff[rt] + koff);
        if (!ok[rt]) {
#pragma unroll
          for (int e = 0; e < 8; ++e) { ah[rt][e] = (f16)0; al[rt][e] = (f16)0; }
        }
      }
#pragma unroll
      for (int nt = 0; nt < 8; ++nt) {
        const int n = o0 + nt * 16 + lo;
        const int64_t wi = (int64_t)j * 131072 + (int64_t)n * 128 + koff;
        f16x8 bh = ldfrag(Wh + wi);
        f16x8 bl = ldfrag(Wl + wi);
#pragma unroll
        for (int rt = 0; rt < 2; ++rt) {
          aq[rt][nt] = MFMA16(ah[rt], bh, aq[rt][nt]);
          aq[rt][nt] = MFMA16(ah[rt], bl, aq[rt][nt]);
          aq[rt][nt] = MFMA16(al[rt], bh, aq[rt][nt]);
        }
      }
    }
  }

  const float SC = 0.29730177875068026f;  // 128^-0.25
#pragma unroll
  for (int nt = 0; nt < 8; ++nt) {
    const int o = o0 + nt * 16 + lo;
    const float vb = bias[o];
#pragma unroll
    for (int rt = 0; rt < 2; ++rt)
#pragma unroll
      for (int r = 0; r < 4; ++r) aq[rt][nt][r] = (aq[rt][nt][r] + vb) * SC;
  }

  if (!isK) {
    STAGE_QK(q3h, (f16)aq[rt][nt][r])
    STAGE_QK(q3l, (f16)(aq[rt][nt][r] - (float)(f16)aq[rt][nt][r]))
  } else {
    STAGE_QK(k3h, (f16)aq[rt][nt][r])
    STAGE_QK(k3l, (f16)(aq[rt][nt][r] - (float)(f16)aq[rt][nt][r]))
  }
}

// ---------------- K234: fused scores + top-64/softmax + PV -----------------
// One block = 16 t2-rows x full 1024 cols of one m. S in LDS fp32 (stride
// 1028). Phase 2: ballot-based exact fp32 top-64 (scalar-pipe counting, no
// shuffle chains in the search), stabilizer = 64th-largest value (softmax
// shift-invariant), P written back as f16 in place. Phase 3: ds_read_b128
// A-frags + MFMA.
__global__ __launch_bounds__(256) void k234_attn(
    const f16* __restrict__ q3h, const f16* __restrict__ q3l,
    const f16* __restrict__ k3h, const f16* __restrict__ k3l,
    const f16* __restrict__ v3T, f16* __restrict__ A) {
  __shared__ float S[16 * 1028];  // 65,792 B
  const int tid = threadIdx.x;
  const int w = tid >> 6, lane = tid & 63;
  const int quad = lane >> 4, lo = lane & 15;
  const int m = blockIdx.y;
  const int r0 = blockIdx.x * 16;  // t2-row tile

  // ---- phase 1: S = Q3 @ K3^T (split-f16, fp32 acc) ----
  {
    f32x4 acc[16];
#pragma unroll
    for (int i = 0; i < 16; ++i)
#pragma unroll
      for (int r = 0; r < 4; ++r) acc[i][r] = 0.f;

    const int64_t qoff = ((int64_t)m * 1024 + r0 + lo) * 128;
#pragma unroll
    for (int kk = 0; kk < 4; ++kk) {
      const int koff = kk * 32 + quad * 8;
      f16x8 ah = ldfrag(q3h + qoff + koff);
      f16x8 al = ldfrag(q3l + qoff + koff);
#pragma unroll
      for (int nt = 0; nt < 16; ++nt) {
        const int col = w * 256 + nt * 16 + lo;
        const int64_t bi = ((int64_t)m * 1024 + col) * 128 + koff;
        f16x8 bh = ldfrag(k3h + bi);
        f16x8 bl = ldfrag(k3l + bi);
        acc[nt] = MFMA16(ah, bh, acc[nt]);
        acc[nt] = MFMA16(ah, bl, acc[nt]);
        acc[nt] = MFMA16(al, bh, acc[nt]);
      }
    }
#pragma unroll
    for (int nt = 0; nt < 16; ++nt)
#pragma unroll
      for (int r = 0; r < 4; ++r)
        S[(quad * 4 + r) * 1028 + w * 256 + nt * 16 + lo] = acc[nt][r];
  }
  __syncthreads();

  // ---- phase 2: exact fp32 top-64 + rowmin + causal + softmax -> f16 P ----
  for (int rr = 0; rr < 4; ++rr) {
    const int row = w * 4 + rr;
    const int t2 = r0 + row;
    const float* srow = S + row * 1028;

    unsigned key[16];
    unsigned kminl = 0xFFFFFFFFu;
#pragma unroll
    for (int i = 0; i < 16; ++i) {
      const unsigned u = __builtin_bit_cast(unsigned, srow[i * 64 + lane]);
      const unsigned k = (u & 0x80000000u) ? ~u : (u | 0x80000000u);
      key[i] = k;
      kminl = min(kminl, k);
    }
    for (int off = 32; off; off >>= 1)
      kminl = min(kminl, (unsigned)__shfl_xor((int)kminl, off));
    const unsigned umn = (kminl & 0x80000000u) ? (kminl ^ 0x80000000u) : ~kminl;
    const float mn = __builtin_bit_cast(float, umn);  // exact row min

    // largest T with count(key >= T) >= 64 -- ballot/popc, scalar-pipe sum
    unsigned long long blo = 0ull, bhi = 0xFFFFFFFFull;
    while (blo < bhi) {
      const unsigned mid = (unsigned)(blo + ((bhi - blo + 1) >> 1));
      int cnt = 0;
#pragma unroll
      for (int i = 0; i < 16; ++i)
        cnt += (int)__popcll(__ballot(key[i] >= mid));
      if (cnt >= 64) blo = mid; else bhi = mid - 1;
    }
    const unsigned kth = (unsigned)blo;
    const unsigned ukv = (kth & 0x80000000u) ? (kth ^ 0x80000000u) : ~kth;
    const float kv = __builtin_bit_cast(float, ukv);  // 64th-largest value

    float ev[16];
    float sum = 0.f;
#pragma unroll
    for (int i = 0; i < 16; ++i) {
      const int s = i * 64 + lane;
      const unsigned k = key[i];
      const unsigned uu = (k & 0x80000000u) ? (k ^ 0x80000000u) : ~k;
      const float f = __builtin_bit_cast(float, uu);
      const float ww = (k >= kth) ? f : mn;
      const float x = (s <= t2) ? __expf(ww - kv) : 0.f;  // kv-stabilized
      ev[i] = x;
      sum += x;
    }
    for (int off = 32; off; off >>= 1) sum += __shfl_xor(sum, off);
    const float inv = 1.0f / sum;

    f16* prow = (f16*)S + row * 2056;  // in-place: first half of this row
#pragma unroll
    for (int i = 0; i < 16; ++i) prow[i * 64 + lane] = (f16)(ev[i] * inv);
  }
  __syncthreads();

  // ---- phase 3: A-tile = P @ V (K = 1024), f16 A-frags straight from LDS --
  {
    const f16* P16 = (const f16*)S;
    f32x4 oacc[2];
#pragma unroll
    for (int nt = 0; nt < 2; ++nt)
#pragma unroll
      for (int r = 0; r < 4; ++r) oacc[nt][r] = 0.f;

    for (int ks = 0; ks < 32; ++ks) {
      const int k0 = ks * 32 + quad * 8;
      f16x8 a = *(const f16x8*)(P16 + lo * 2056 + k0);
#pragma unroll
      for (int nt = 0; nt < 2; ++nt) {
        const int kc = w * 32 + nt * 16 + lo;
        f16x8 fb = ldfrag(v3T + ((int64_t)m * 128 + kc) * 1024 + k0);
        oacc[nt] = MFMA16(a, fb, oacc[nt]);
      }
    }
#pragma unroll
    for (int nt = 0; nt < 2; ++nt)
#pragma unroll
      for (int r = 0; r < 4; ++r) {
        const int row = r0 + quad * 4 + r, col = w * 32 + nt * 16 + lo;
        A[((int64_t)m * 1024 + row) * 128 + col] = (f16)oacc[nt][r];
      }
  }
}

// ---------------- K5: gather + output projection + bias --------------------
__global__ __launch_bounds__(256) void k5_proj(
    const f16* __restrict__ A, const f16* __restrict__ Wub,
    const float* __restrict__ bu, float* __restrict__ out) {
  const int w = threadIdx.x >> 6, lane = threadIdx.x & 63;
  const int quad = lane >> 4, lo = lane & 15;
  const int r0 = blockIdx.x * 64 + w * 16;  // row in [0, 8192) = b*1024 + t2
  const int r = r0 + lo;
  const int bI = r >> 10, t2 = r & 1023;

  f32x4 acc[8];
#pragma unroll
  for (int i = 0; i < 8; ++i)
#pragma unroll
    for (int rr = 0; rr < 4; ++rr) acc[i][rr] = 0.f;

  for (int kk = 0; kk < 32; ++kk) {
    const int o = kk * 32 + quad * 8;  // feature index 0..1023
    const int j = o >> 7, kc = o & 127;
    f16x8 a = ldfrag(A + (((int64_t)(bI * 8 + j) * 1024 + t2) * 128 + kc));
#pragma unroll
    for (int nt = 0; nt < 8; ++nt) {
      f16x8 fb = ldfrag(Wub + (int64_t)(nt * 16 + lo) * 1024 + o);
      acc[nt] = MFMA16(a, fb, acc[nt]);
    }
  }
#pragma unroll
  for (int nt = 0; nt < 8; ++nt) {
    const int col = nt * 16 + lo;
    const float bias = bu[col];
#pragma unroll
    for (int rr = 0; rr < 4; ++rr) {
      const int row = r0 + quad * 4 + rr;
      out[(int64_t)row * 128 + col] = acc[nt][rr] + bias;
    }
  }
}

// ---------------- launcher --------------------------------------------------
extern "C" void kernel_launch(void* const* d_in, const int* in_sizes, int n_in,
                              void* d_out, int out_size, void* d_ws, size_t ws_size,
                              hipStream_t stream) {
  const float* x  = (const float*)d_in[0];
  const float* Wq = (const float*)d_in[1];
  const float* bq = (const float*)d_in[2];
  const float* Wk = (const float*)d_in[3];
  const float* bk = (const float*)d_in[4];
  const float* Wv = (const float*)d_in[5];
  const float* bv = (const float*)d_in[6];
  const float* Wu = (const float*)d_in[7];
  const float* bu = (const float*)d_in[8];
  float* out = (float*)d_out;

  char* ws = (char*)d_ws;
  f16* xh  = (f16*)ws;  ws += 2097152;
  f16* xl  = (f16*)ws;  ws += 2097152;
  f16* Wqh = (f16*)ws;  ws += 1310720;
  f16* Wql = (f16*)ws;  ws += 1310720;
  f16* Wkh = (f16*)ws;  ws += 1310720;
  f16* Wkl = (f16*)ws;  ws += 1310720;
  f16* Wvb = (f16*)ws;  ws += 262144;
  f16* Wub = (f16*)ws;  ws += 262144;
  f16* q3h = (f16*)ws;  ws += 16777216;           // 64*1024*128 fp16
  f16* q3l = (f16*)ws;  ws += 16777216;
  f16* k3h = (f16*)ws;  ws += 16777216;
  f16* k3l = (f16*)ws;  ws += 16777216;
  f16* v3T = (f16*)ws;  ws += 16777216;
  f16* A   = (f16*)ws;  ws += 16777216;           // total ~105.5 MB

  // K0: repack (exactly 2621440 threads = 10240 * 256)
  k0_prep<<<10240, 256, 0, stream>>>(x, Wq, Wk, Wv, Wu,
                                     xh, xl, Wqh, Wql, Wkh, Wkl, Wvb, Wub);

  // K1: convs + scramble; (row-tile, ch-half, Q/K) blocks of 4 waves
  k1_conv<<<dim3(256, 2, 2), 256, 0, stream>>>(xh, xl, Wqh, Wql, Wkh, Wkl, Wvb,
                                               bq, bk, bv, q3h, q3l, k3h, k3l,
                                               v3T);

  // K234: fused scores + selection/softmax + PV, one launch
  k234_attn<<<dim3(64, 64), 256, 0, stream>>>(q3h, q3l, k3h, k3l, v3T, A);

  // K5: projection (8192 rows / 64 per block)
  k5_proj<<<128, 256, 0, stream>>>(A, Wub, bu, out);

  (void)in_sizes; (void)n_in; (void)out_size; (void)ws_size;
}

// Round 6
// 780.464 us; speedup vs baseline: 1.3871x; 1.2682x over previous
//
#include <hip/hip_runtime.h>
#include <hip/hip_fp16.h>
#include <cstdint>

using f16 = _Float16;
typedef __attribute__((ext_vector_type(8))) _Float16 f16x8;
typedef __attribute__((ext_vector_type(4))) float f32x4;

#define MFMA16(a, b, c) __builtin_amdgcn_mfma_f32_16x16x32_f16((a), (b), (c), 0, 0, 0)

__device__ __forceinline__ f16x8 ldfrag(const f16* p) { return *(const f16x8*)p; }

// Problem constants: B=8, T=1024, K=128, H=8 -> M = B*H = 64 scrambled batches.
static const int64_t NX = 1048576;   // x elements: 8*1024*128
static const int64_t NW = 655360;    // Wq/Wk elements: 1024*128*5
static const int64_t NV = 131072;    // Wv / Wu elements: 1024*128

// ---------------- K0: split-convert/repack weights and x to fp16 hi/lo -----
__global__ __launch_bounds__(256) void k0_prep(
    const float* __restrict__ x, const float* __restrict__ Wq,
    const float* __restrict__ Wk, const float* __restrict__ Wv,
    const float* __restrict__ Wu,
    f16* __restrict__ xh, f16* __restrict__ xl,
    f16* __restrict__ Wqh, f16* __restrict__ Wql,
    f16* __restrict__ Wkh, f16* __restrict__ Wkl,
    f16* __restrict__ Wvb, f16* __restrict__ Wub) {
  int64_t i = (int64_t)blockIdx.x * 256 + threadIdx.x;  // grid sized exactly
  if (i < NX) {
    const float v = x[i];
    const f16 h = (f16)v;
    xh[i] = h; xl[i] = (f16)(v - (float)h);
  } else if (i < NX + NW) {
    int64_t d = i - NX;
    int j = (int)(d >> 17);
    int rem = (int)(d & 131071);
    int o = rem >> 7, c = rem & 127;
    const float v = Wq[(int64_t)(o * 128 + c) * 5 + j];   // layout [j][o][c]
    const f16 h = (f16)v;
    Wqh[d] = h; Wql[d] = (f16)(v - (float)h);
  } else if (i < NX + 2 * NW) {
    int64_t d = i - NX - NW;
    int j = (int)(d >> 17);
    int rem = (int)(d & 131071);
    int o = rem >> 7, c = rem & 127;
    const float v = Wk[(int64_t)(o * 128 + c) * 5 + j];
    const f16 h = (f16)v;
    Wkh[d] = h; Wkl[d] = (f16)(v - (float)h);
  } else if (i < NX + 2 * NW + NV) {
    int64_t d = i - NX - 2 * NW;
    Wvb[d] = (f16)Wv[d];                                // [o][c]
  } else {
    int64_t d = i - NX - 2 * NW - NV;
    Wub[d] = (f16)Wu[d];                                // [c][o]
  }
}

// ---------------- K1: causal convs (split-f16) + LDS-staged coalesced out --
// blockIdx = (row-tile of 32, channel-half of 512, Q-or-K). 256 thr = 4 waves,
// each wave owns 128 channels. Q-blocks also compute V (pointwise).
// q3/k3: [m=64][t2=1024][kc=128] hi+lo fp16 (scaled); v3T: [m][kc][t2] fp16.
#define STAGE_QK(DST, VALEXPR)                                          \
  {                                                                     \
    __syncthreads();                                                    \
    _Pragma("unroll")                                                   \
    for (int nt = 0; nt < 8; ++nt) {                                    \
      const int o = o0 + nt * 16 + lo;                                  \
      const int kcl = (o >> 3) & 63, hh = o & 7;                        \
      _Pragma("unroll")                                                 \
      for (int rt = 0; rt < 2; ++rt) {                                  \
        _Pragma("unroll")                                               \
        for (int r = 0; r < 4; ++r) {                                   \
          const int t2l = (rt * 16 + quad * 4 + r) * 8 + hh;            \
          lds[t2l * 72 + kcl] = (VALEXPR);                              \
        }                                                               \
      }                                                                 \
    }                                                                   \
    __syncthreads();                                                    \
    _Pragma("unroll")                                                   \
    for (int p = 0; p < 8; ++p) {                                       \
      const int idx = p * 256 + tid;                                    \
      const int a = idx >> 3, c8 = (idx & 7) * 8;                       \
      *(f16x8*)(DST + ((int64_t)m * 1024 + t2b + a) * 128 +             \
                half * 64 + c8) = *(const f16x8*)&lds[a * 72 + c8];     \
    }                                                                   \
  }

__global__ __launch_bounds__(256) void k1_conv(
    const f16* __restrict__ xh, const f16* __restrict__ xl,
    const f16* __restrict__ Wqh, const f16* __restrict__ Wql,
    const f16* __restrict__ Wkh, const f16* __restrict__ Wkl,
    const f16* __restrict__ Wvb,
    const float* __restrict__ bq, const float* __restrict__ bk,
    const float* __restrict__ bv,
    f16* __restrict__ q3h, f16* __restrict__ q3l,
    f16* __restrict__ k3h, f16* __restrict__ k3l,
    f16* __restrict__ v3T) {
  __shared__ f16 lds[18432];  // max(256*72, 64*264) elems = 36.9 KB
  const int tid = threadIdx.x;
  const int w = tid >> 6, lane = tid & 63;
  const int quad = lane >> 4, lo = lane & 15;
  const int r0 = blockIdx.x * 32;     // rows r0..r0+31 (same b, same m)
  const int bb = r0 >> 10;
  const int m  = r0 >> 7;
  const int t2b = (r0 & 127) * 8;
  const int half = blockIdx.y;        // which 512-channel half
  const int isK = blockIdx.z;         // 0 = Q (+V), 1 = K
  const int o0 = half * 512 + w * 128;

  const f16* Wh = isK ? Wkh : Wqh;
  const f16* Wl = isK ? Wkl : Wql;
  const float* bias = isK ? bk : bq;

  // ---- V pass (Q-blocks only): 1 tap, hi only ----
  if (!isK) {
    f32x4 av[2][8];
#pragma unroll
    for (int rt = 0; rt < 2; ++rt)
#pragma unroll
      for (int i = 0; i < 8; ++i)
#pragma unroll
        for (int r = 0; r < 4; ++r) av[rt][i][r] = 0.f;

#pragma unroll
    for (int kk = 0; kk < 4; ++kk) {
      const int koff = kk * 32 + quad * 8;
      f16x8 ah[2];
#pragma unroll
      for (int rt = 0; rt < 2; ++rt) {
        const int tt = (r0 + rt * 16 + lo) & 1023;
        ah[rt] = ldfrag(xh + ((int64_t)(bb * 1024 + tt)) * 128 + koff);
      }
#pragma unroll
      for (int nt = 0; nt < 8; ++nt) {
        const int n = o0 + nt * 16 + lo;
        f16x8 bv8 = ldfrag(Wvb + (int64_t)n * 128 + koff);
        av[0][nt] = MFMA16(ah[0], bv8, av[0][nt]);
        av[1][nt] = MFMA16(ah[1], bv8, av[1][nt]);
      }
    }
    // stage v3T via LDS [kcl][t2l] (stride 264), coalesced out
#pragma unroll
    for (int nt = 0; nt < 8; ++nt) {
      const int o = o0 + nt * 16 + lo;
      const float vbv = bv[o];
      const int kcl = (o >> 3) & 63, hh = o & 7;
#pragma unroll
      for (int rt = 0; rt < 2; ++rt)
#pragma unroll
        for (int r = 0; r < 4; ++r) {
          const int t2l = (rt * 16 + quad * 4 + r) * 8 + hh;
          lds[kcl * 264 + t2l] = (f16)(av[rt][nt][r] + vbv);
        }
    }
    __syncthreads();
#pragma unroll
    for (int p = 0; p < 8; ++p) {
      const int idx = p * 256 + tid;
      const int kcl = idx >> 5, t8 = (idx & 31) * 8;
      *(f16x8*)(v3T + ((int64_t)m * 128 + half * 64 + kcl) * 1024 + t2b + t8) =
          *(const f16x8*)&lds[kcl * 264 + t8];
    }
  }

  // ---- Q or K main loop: 5 taps, split-f16 (3 MFMAs per tap) ----
  f32x4 aq[2][8];
#pragma unroll
  for (int rt = 0; rt < 2; ++rt)
#pragma unroll
    for (int i = 0; i < 8; ++i)
#pragma unroll
      for (int r = 0; r < 4; ++r) aq[rt][i][r] = 0.f;

#pragma unroll
  for (int j = 0; j < 5; ++j) {
    bool ok[2]; int64_t xoff[2];
#pragma unroll
    for (int rt = 0; rt < 2; ++rt) {
      const int tt = (r0 + rt * 16 + lo) & 1023;
      const int tp = tt + j - 4;            // causal left-pad 4
      ok[rt] = (tp >= 0);
      xoff[rt] = ((int64_t)(bb * 1024 + (ok[rt] ? tp : 0))) * 128;
    }
#pragma unroll
    for (int kk = 0; kk < 4; ++kk) {
      const int koff = kk * 32 + quad * 8;
      f16x8 ah[2], al[2];
#pragma unroll
      for (int rt = 0; rt < 2; ++rt) {
        ah[rt] = ldfrag(xh + xoff[rt] + koff);
        al[rt] = ldfrag(xl + xoff[rt] + koff);
        if (!ok[rt]) {
#pragma unroll
          for (int e = 0; e < 8; ++e) { ah[rt][e] = (f16)0; al[rt][e] = (f16)0; }
        }
      }
#pragma unroll
      for (int nt = 0; nt < 8; ++nt) {
        const int n = o0 + nt * 16 + lo;
        const int64_t wi = (int64_t)j * 131072 + (int64_t)n * 128 + koff;
        f16x8 bh = ldfrag(Wh + wi);
        f16x8 bl = ldfrag(Wl + wi);
#pragma unroll
        for (int rt = 0; rt < 2; ++rt) {
          aq[rt][nt] = MFMA16(ah[rt], bh, aq[rt][nt]);
          aq[rt][nt] = MFMA16(ah[rt], bl, aq[rt][nt]);
          aq[rt][nt] = MFMA16(al[rt], bh, aq[rt][nt]);
        }
      }
    }
  }

  const float SC = 0.29730177875068026f;  // 128^-0.25
#pragma unroll
  for (int nt = 0; nt < 8; ++nt) {
    const int o = o0 + nt * 16 + lo;
    const float vb = bias[o];
#pragma unroll
    for (int rt = 0; rt < 2; ++rt)
#pragma unroll
      for (int r = 0; r < 4; ++r) aq[rt][nt][r] = (aq[rt][nt][r] + vb) * SC;
  }

  if (!isK) {
    STAGE_QK(q3h, (f16)aq[rt][nt][r])
    STAGE_QK(q3l, (f16)(aq[rt][nt][r] - (float)(f16)aq[rt][nt][r]))
  } else {
    STAGE_QK(k3h, (f16)aq[rt][nt][r])
    STAGE_QK(k3l, (f16)(aq[rt][nt][r] - (float)(f16)aq[rt][nt][r]))
  }
}

// ---------------- K234: fused scores + top-64/softmax + PV -----------------
// 512 threads (8 waves), 16 t2-rows x full 1024 cols of one m. S in LDS fp32
// (stride 1028), 65.8 KB -> 2 blocks/CU = 16 waves/CU. Phase 2: bit-by-bit
// exact fp32 top-64 threshold (fixed 32 iterations, 2 rows interleaved for
// ILP), stabilizer = 64th-largest value, P written back in place as f16.
__global__ __launch_bounds__(512, 4) void k234_attn(
    const f16* __restrict__ q3h, const f16* __restrict__ q3l,
    const f16* __restrict__ k3h, const f16* __restrict__ k3l,
    const f16* __restrict__ v3T, f16* __restrict__ A) {
  __shared__ float S[16 * 1028];  // 65,792 B
  const int tid = threadIdx.x;
  const int w = tid >> 6, lane = tid & 63;
  const int quad = lane >> 4, lo = lane & 15;
  const int m = blockIdx.y;
  const int r0 = blockIdx.x * 16;  // t2-row tile

  // ---- phase 1: S = Q3 @ K3^T (split-f16, fp32 acc); wave w -> 128 cols ---
  {
    f32x4 acc[8];
#pragma unroll
    for (int i = 0; i < 8; ++i)
#pragma unroll
      for (int r = 0; r < 4; ++r) acc[i][r] = 0.f;

    const int64_t qoff = ((int64_t)m * 1024 + r0 + lo) * 128;
#pragma unroll
    for (int kk = 0; kk < 4; ++kk) {
      const int koff = kk * 32 + quad * 8;
      f16x8 ah = ldfrag(q3h + qoff + koff);
      f16x8 al = ldfrag(q3l + qoff + koff);
#pragma unroll
      for (int nt = 0; nt < 8; ++nt) {
        const int col = w * 128 + nt * 16 + lo;
        const int64_t bi = ((int64_t)m * 1024 + col) * 128 + koff;
        f16x8 bh = ldfrag(k3h + bi);
        f16x8 bl = ldfrag(k3l + bi);
        acc[nt] = MFMA16(ah, bh, acc[nt]);
        acc[nt] = MFMA16(ah, bl, acc[nt]);
        acc[nt] = MFMA16(al, bh, acc[nt]);
      }
    }
#pragma unroll
    for (int nt = 0; nt < 8; ++nt)
#pragma unroll
      for (int r = 0; r < 4; ++r)
        S[(quad * 4 + r) * 1028 + w * 128 + nt * 16 + lo] = acc[nt][r];
  }
  __syncthreads();

  // ---- phase 2: exact fp32 top-64 + rowmin + causal + softmax -> f16 P ----
  // wave w owns rows {2w, 2w+1}; both searches interleaved for ILP.
  {
    const int row0 = w * 2;
    unsigned key[2][16];
    unsigned kmn0 = 0xFFFFFFFFu, kmn1 = 0xFFFFFFFFu;
#pragma unroll
    for (int i = 0; i < 16; ++i) {
      const unsigned u0 =
          __builtin_bit_cast(unsigned, S[row0 * 1028 + i * 64 + lane]);
      const unsigned u1 =
          __builtin_bit_cast(unsigned, S[(row0 + 1) * 1028 + i * 64 + lane]);
      const unsigned k0v = (u0 & 0x80000000u) ? ~u0 : (u0 | 0x80000000u);
      const unsigned k1v = (u1 & 0x80000000u) ? ~u1 : (u1 | 0x80000000u);
      key[0][i] = k0v; key[1][i] = k1v;
      kmn0 = min(kmn0, k0v); kmn1 = min(kmn1, k1v);
    }
#pragma unroll
    for (int off = 32; off; off >>= 1) {
      kmn0 = min(kmn0, (unsigned)__shfl_xor((int)kmn0, off));
      kmn1 = min(kmn1, (unsigned)__shfl_xor((int)kmn1, off));
    }

    // bit-by-bit max T with count(key >= T) >= 64 (exact 64th-largest key)
    unsigned th0 = 0u, th1 = 0u;
    for (int b = 31; b >= 0; --b) {
      const unsigned c0 = th0 | (1u << b);
      const unsigned c1 = th1 | (1u << b);
      int cnt0 = 0, cnt1 = 0;
#pragma unroll
      for (int i = 0; i < 16; ++i) {
        cnt0 += (int)__popcll(__ballot(key[0][i] >= c0));
        cnt1 += (int)__popcll(__ballot(key[1][i] >= c1));
      }
      if (cnt0 >= 64) th0 = c0;
      if (cnt1 >= 64) th1 = c1;
    }

#pragma unroll
    for (int rr = 0; rr < 2; ++rr) {
      const unsigned kth = rr ? th1 : th0;
      const unsigned kmn = rr ? kmn1 : kmn0;
      const int row = row0 + rr, t2 = r0 + row;
      const unsigned umn = (kmn & 0x80000000u) ? (kmn ^ 0x80000000u) : ~kmn;
      const float mn = __builtin_bit_cast(float, umn);   // exact row min
      const unsigned ukv = (kth & 0x80000000u) ? (kth ^ 0x80000000u) : ~kth;
      const float kv = __builtin_bit_cast(float, ukv);   // 64th-largest value

      float ev[16];
      float sum = 0.f;
#pragma unroll
      for (int i = 0; i < 16; ++i) {
        const int s = i * 64 + lane;
        const unsigned k = key[rr][i];
        const unsigned uu = (k & 0x80000000u) ? (k ^ 0x80000000u) : ~k;
        const float f = __builtin_bit_cast(float, uu);
        const float ww = (k >= kth) ? f : mn;
        const float x = (s <= t2) ? __expf(ww - kv) : 0.f;  // kv-stabilized
        ev[i] = x;
        sum += x;
      }
      for (int off = 32; off; off >>= 1) sum += __shfl_xor(sum, off);
      const float inv = 1.0f / sum;

      f16* prow = (f16*)S + row * 2056;  // in-place over this row's fp32
#pragma unroll
      for (int i = 0; i < 16; ++i) prow[i * 64 + lane] = (f16)(ev[i] * inv);
    }
  }
  __syncthreads();

  // ---- phase 3: A-tile = P @ V (K = 1024); wave w -> 16 kc columns --------
  {
    const f16* P16 = (const f16*)S;
    f32x4 oacc;
#pragma unroll
    for (int r = 0; r < 4; ++r) oacc[r] = 0.f;
    const int kc = w * 16 + lo;
    const f16* vb = v3T + ((int64_t)m * 128 + kc) * 1024;
#pragma unroll 4
    for (int ks = 0; ks < 32; ++ks) {
      const int k0 = ks * 32 + quad * 8;
      f16x8 a = *(const f16x8*)(P16 + lo * 2056 + k0);
      f16x8 fb = ldfrag(vb + k0);
      oacc = MFMA16(a, fb, oacc);
    }
#pragma unroll
    for (int r = 0; r < 4; ++r) {
      const int row = r0 + quad * 4 + r;
      A[((int64_t)m * 1024 + row) * 128 + kc] = (f16)oacc[r];
    }
  }
}

// ---------------- K5: gather + output projection + bias --------------------
__global__ __launch_bounds__(256) void k5_proj(
    const f16* __restrict__ A, const f16* __restrict__ Wub,
    const float* __restrict__ bu, float* __restrict__ out) {
  const int w = threadIdx.x >> 6, lane = threadIdx.x & 63;
  const int quad = lane >> 4, lo = lane & 15;
  const int r0 = blockIdx.x * 64 + w * 16;  // row in [0, 8192) = b*1024 + t2
  const int r = r0 + lo;
  const int bI = r >> 10, t2 = r & 1023;

  f32x4 acc[8];
#pragma unroll
  for (int i = 0; i < 8; ++i)
#pragma unroll
    for (int rr = 0; rr < 4; ++rr) acc[i][rr] = 0.f;

  for (int kk = 0; kk < 32; ++kk) {
    const int o = kk * 32 + quad * 8;  // feature index 0..1023
    const int j = o >> 7, kc = o & 127;
    f16x8 a = ldfrag(A + (((int64_t)(bI * 8 + j) * 1024 + t2) * 128 + kc));
#pragma unroll
    for (int nt = 0; nt < 8; ++nt) {
      f16x8 fb = ldfrag(Wub + (int64_t)(nt * 16 + lo) * 1024 + o);
      acc[nt] = MFMA16(a, fb, acc[nt]);
    }
  }
#pragma unroll
  for (int nt = 0; nt < 8; ++nt) {
    const int col = nt * 16 + lo;
    const float bias = bu[col];
#pragma unroll
    for (int rr = 0; rr < 4; ++rr) {
      const int row = r0 + quad * 4 + rr;
      out[(int64_t)row * 128 + col] = acc[nt][rr] + bias;
    }
  }
}

// ---------------- launcher --------------------------------------------------
extern "C" void kernel_launch(void* const* d_in, const int* in_sizes, int n_in,
                              void* d_out, int out_size, void* d_ws, size_t ws_size,
                              hipStream_t stream) {
  const float* x  = (const float*)d_in[0];
  const float* Wq = (const float*)d_in[1];
  const float* bq = (const float*)d_in[2];
  const float* Wk = (const float*)d_in[3];
  const float* bk = (const float*)d_in[4];
  const float* Wv = (const float*)d_in[5];
  const float* bv = (const float*)d_in[6];
  const float* Wu = (const float*)d_in[7];
  const float* bu = (const float*)d_in[8];
  float* out = (float*)d_out;

  char* ws = (char*)d_ws;
  f16* xh  = (f16*)ws;  ws += 2097152;
  f16* xl  = (f16*)ws;  ws += 2097152;
  f16* Wqh = (f16*)ws;  ws += 1310720;
  f16* Wql = (f16*)ws;  ws += 1310720;
  f16* Wkh = (f16*)ws;  ws += 1310720;
  f16* Wkl = (f16*)ws;  ws += 1310720;
  f16* Wvb = (f16*)ws;  ws += 262144;
  f16* Wub = (f16*)ws;  ws += 262144;
  f16* q3h = (f16*)ws;  ws += 16777216;           // 64*1024*128 fp16
  f16* q3l = (f16*)ws;  ws += 16777216;
  f16* k3h = (f16*)ws;  ws += 16777216;
  f16* k3l = (f16*)ws;  ws += 16777216;
  f16* v3T = (f16*)ws;  ws += 16777216;
  f16* A   = (f16*)ws;  ws += 16777216;           // total ~105.5 MB

  // K0: repack (exactly 2621440 threads = 10240 * 256)
  k0_prep<<<10240, 256, 0, stream>>>(x, Wq, Wk, Wv, Wu,
                                     xh, xl, Wqh, Wql, Wkh, Wkl, Wvb, Wub);

  // K1: convs + scramble; (row-tile, ch-half, Q/K) blocks of 4 waves
  k1_conv<<<dim3(256, 2, 2), 256, 0, stream>>>(xh, xl, Wqh, Wql, Wkh, Wkl, Wvb,
                                               bq, bk, bv, q3h, q3l, k3h, k3l,
                                               v3T);

  // K234: fused scores + selection/softmax + PV, 512-thread blocks
  k234_attn<<<dim3(64, 64), 512, 0, stream>>>(q3h, q3l, k3h, k3l, v3T, A);

  // K5: projection (8192 rows / 64 per block)
  k5_proj<<<128, 256, 0, stream>>>(A, Wub, bu, out);

  (void)in_sizes; (void)n_in; (void)out_size; (void)ws_size;
}

// Round 7
// 768.686 us; speedup vs baseline: 1.4084x; 1.0153x over previous
//
#include <hip/hip_runtime.h>
#include <hip/hip_fp16.h>
#include <cstdint>

using f16 = _Float16;
typedef __attribute__((ext_vector_type(8))) _Float16 f16x8;
typedef __attribute__((ext_vector_type(4))) _Float16 f16x4;
typedef __attribute__((ext_vector_type(4))) float f32x4;

#define MFMA16(a, b, c) __builtin_amdgcn_mfma_f32_16x16x32_f16((a), (b), (c), 0, 0, 0)

__device__ __forceinline__ f16x8 ldfrag(const f16* p) { return *(const f16x8*)p; }

// Problem constants: B=8, T=1024, K=128, H=8 -> M = B*H = 64 scrambled batches.
static const int64_t NX = 1048576;   // x elements: 8*1024*128
static const int64_t NW = 655360;    // Wq/Wk elements: 1024*128*5
static const int64_t NV = 131072;    // Wv / Wu elements: 1024*128

// ---------------- K0: split-convert/repack weights and x to fp16 hi/lo -----
__global__ __launch_bounds__(256) void k0_prep(
    const float* __restrict__ x, const float* __restrict__ Wq,
    const float* __restrict__ Wk, const float* __restrict__ Wv,
    const float* __restrict__ Wu,
    f16* __restrict__ xh, f16* __restrict__ xl,
    f16* __restrict__ Wqh, f16* __restrict__ Wql,
    f16* __restrict__ Wkh, f16* __restrict__ Wkl,
    f16* __restrict__ Wvb, f16* __restrict__ Wub) {
  int64_t i = (int64_t)blockIdx.x * 256 + threadIdx.x;  // grid sized exactly
  if (i < NX) {
    const float v = x[i];
    const f16 h = (f16)v;
    xh[i] = h; xl[i] = (f16)(v - (float)h);
  } else if (i < NX + NW) {
    int64_t d = i - NX;
    int j = (int)(d >> 17);
    int rem = (int)(d & 131071);
    int o = rem >> 7, c = rem & 127;
    const float v = Wq[(int64_t)(o * 128 + c) * 5 + j];   // layout [j][o][c]
    const f16 h = (f16)v;
    Wqh[d] = h; Wql[d] = (f16)(v - (float)h);
  } else if (i < NX + 2 * NW) {
    int64_t d = i - NX - NW;
    int j = (int)(d >> 17);
    int rem = (int)(d & 131071);
    int o = rem >> 7, c = rem & 127;
    const float v = Wk[(int64_t)(o * 128 + c) * 5 + j];
    const f16 h = (f16)v;
    Wkh[d] = h; Wkl[d] = (f16)(v - (float)h);
  } else if (i < NX + 2 * NW + NV) {
    int64_t d = i - NX - 2 * NW;
    Wvb[d] = (f16)Wv[d];                                // [o][c]
  } else {
    int64_t d = i - NX - 2 * NW - NV;
    Wub[d] = (f16)Wu[d];                                // [c][o]
  }
}

// ---------------- K1: causal convs (split-f16) + LDS-staged coalesced out --
// blockIdx = (row-tile of 32, channel-half of 512, Q-or-K). 256 thr = 4 waves,
// each wave owns 128 channels. Q-blocks also compute V (pointwise).
// q3/k3: [m=64][t2=1024][kc=128] hi+lo fp16 (scaled); v3T: [m][kc][t2] fp16.
#define STAGE_QK(DST, VALEXPR)                                          \
  {                                                                     \
    __syncthreads();                                                    \
    _Pragma("unroll")                                                   \
    for (int nt = 0; nt < 8; ++nt) {                                    \
      const int o = o0 + nt * 16 + lo;                                  \
      const int kcl = (o >> 3) & 63, hh = o & 7;                        \
      _Pragma("unroll")                                                 \
      for (int rt = 0; rt < 2; ++rt) {                                  \
        _Pragma("unroll")                                               \
        for (int r = 0; r < 4; ++r) {                                   \
          const int t2l = (rt * 16 + quad * 4 + r) * 8 + hh;            \
          lds[t2l * 72 + kcl] = (VALEXPR);                              \
        }                                                               \
      }                                                                 \
    }                                                                   \
    __syncthreads();                                                    \
    _Pragma("unroll")                                                   \
    for (int p = 0; p < 8; ++p) {                                       \
      const int idx = p * 256 + tid;                                    \
      const int a = idx >> 3, c8 = (idx & 7) * 8;                       \
      *(f16x8*)(DST + ((int64_t)m * 1024 + t2b + a) * 128 +             \
                half * 64 + c8) = *(const f16x8*)&lds[a * 72 + c8];     \
    }                                                                   \
  }

__global__ __launch_bounds__(256) void k1_conv(
    const f16* __restrict__ xh, const f16* __restrict__ xl,
    const f16* __restrict__ Wqh, const f16* __restrict__ Wql,
    const f16* __restrict__ Wkh, const f16* __restrict__ Wkl,
    const f16* __restrict__ Wvb,
    const float* __restrict__ bq, const float* __restrict__ bk,
    const float* __restrict__ bv,
    f16* __restrict__ q3h, f16* __restrict__ q3l,
    f16* __restrict__ k3h, f16* __restrict__ k3l,
    f16* __restrict__ v3T) {
  __shared__ f16 lds[18432];  // max(256*72, 64*264) elems = 36.9 KB
  const int tid = threadIdx.x;
  const int w = tid >> 6, lane = tid & 63;
  const int quad = lane >> 4, lo = lane & 15;
  const int r0 = blockIdx.x * 32;     // rows r0..r0+31 (same b, same m)
  const int bb = r0 >> 10;
  const int m  = r0 >> 7;
  const int t2b = (r0 & 127) * 8;
  const int half = blockIdx.y;        // which 512-channel half
  const int isK = blockIdx.z;         // 0 = Q (+V), 1 = K
  const int o0 = half * 512 + w * 128;

  const f16* Wh = isK ? Wkh : Wqh;
  const f16* Wl = isK ? Wkl : Wql;
  const float* bias = isK ? bk : bq;

  // ---- V pass (Q-blocks only): 1 tap, hi only ----
  if (!isK) {
    f32x4 av[2][8];
#pragma unroll
    for (int rt = 0; rt < 2; ++rt)
#pragma unroll
      for (int i = 0; i < 8; ++i)
#pragma unroll
        for (int r = 0; r < 4; ++r) av[rt][i][r] = 0.f;

#pragma unroll
    for (int kk = 0; kk < 4; ++kk) {
      const int koff = kk * 32 + quad * 8;
      f16x8 ah[2];
#pragma unroll
      for (int rt = 0; rt < 2; ++rt) {
        const int tt = (r0 + rt * 16 + lo) & 1023;
        ah[rt] = ldfrag(xh + ((int64_t)(bb * 1024 + tt)) * 128 + koff);
      }
#pragma unroll
      for (int nt = 0; nt < 8; ++nt) {
        const int n = o0 + nt * 16 + lo;
        f16x8 bv8 = ldfrag(Wvb + (int64_t)n * 128 + koff);
        av[0][nt] = MFMA16(ah[0], bv8, av[0][nt]);
        av[1][nt] = MFMA16(ah[1], bv8, av[1][nt]);
      }
    }
    // stage v3T via LDS [kcl][t2l] (stride 264), coalesced out
#pragma unroll
    for (int nt = 0; nt < 8; ++nt) {
      const int o = o0 + nt * 16 + lo;
      const float vbv = bv[o];
      const int kcl = (o >> 3) & 63, hh = o & 7;
#pragma unroll
      for (int rt = 0; rt < 2; ++rt)
#pragma unroll
        for (int r = 0; r < 4; ++r) {
          const int t2l = (rt * 16 + quad * 4 + r) * 8 + hh;
          lds[kcl * 264 + t2l] = (f16)(av[rt][nt][r] + vbv);
        }
    }
    __syncthreads();
#pragma unroll
    for (int p = 0; p < 8; ++p) {
      const int idx = p * 256 + tid;
      const int kcl = idx >> 5, t8 = (idx & 31) * 8;
      *(f16x8*)(v3T + ((int64_t)m * 128 + half * 64 + kcl) * 1024 + t2b + t8) =
          *(const f16x8*)&lds[kcl * 264 + t8];
    }
  }

  // ---- Q or K main loop: 5 taps, split-f16 (3 MFMAs per tap) ----
  f32x4 aq[2][8];
#pragma unroll
  for (int rt = 0; rt < 2; ++rt)
#pragma unroll
    for (int i = 0; i < 8; ++i)
#pragma unroll
      for (int r = 0; r < 4; ++r) aq[rt][i][r] = 0.f;

#pragma unroll
  for (int j = 0; j < 5; ++j) {
    bool ok[2]; int64_t xoff[2];
#pragma unroll
    for (int rt = 0; rt < 2; ++rt) {
      const int tt = (r0 + rt * 16 + lo) & 1023;
      const int tp = tt + j - 4;            // causal left-pad 4
      ok[rt] = (tp >= 0);
      xoff[rt] = ((int64_t)(bb * 1024 + (ok[rt] ? tp : 0))) * 128;
    }
#pragma unroll
    for (int kk = 0; kk < 4; ++kk) {
      const int koff = kk * 32 + quad * 8;
      f16x8 ah[2], al[2];
#pragma unroll
      for (int rt = 0; rt < 2; ++rt) {
        ah[rt] = ldfrag(xh + xoff[rt] + koff);
        al[rt] = ldfrag(xl + xoff[rt] + koff);
        if (!ok[rt]) {
#pragma unroll
          for (int e = 0; e < 8; ++e) { ah[rt][e] = (f16)0; al[rt][e] = (f16)0; }
        }
      }
#pragma unroll
      for (int nt = 0; nt < 8; ++nt) {
        const int n = o0 + nt * 16 + lo;
        const int64_t wi = (int64_t)j * 131072 + (int64_t)n * 128 + koff;
        f16x8 bh = ldfrag(Wh + wi);
        f16x8 bl = ldfrag(Wl + wi);
#pragma unroll
        for (int rt = 0; rt < 2; ++rt) {
          aq[rt][nt] = MFMA16(ah[rt], bh, aq[rt][nt]);
          aq[rt][nt] = MFMA16(ah[rt], bl, aq[rt][nt]);
          aq[rt][nt] = MFMA16(al[rt], bh, aq[rt][nt]);
        }
      }
    }
  }

  const float SC = 0.29730177875068026f;  // 128^-0.25
#pragma unroll
  for (int nt = 0; nt < 8; ++nt) {
    const int o = o0 + nt * 16 + lo;
    const float vb = bias[o];
#pragma unroll
    for (int rt = 0; rt < 2; ++rt)
#pragma unroll
      for (int r = 0; r < 4; ++r) aq[rt][nt][r] = (aq[rt][nt][r] + vb) * SC;
  }

  if (!isK) {
    STAGE_QK(q3h, (f16)aq[rt][nt][r])
    STAGE_QK(q3l, (f16)(aq[rt][nt][r] - (float)(f16)aq[rt][nt][r]))
  } else {
    STAGE_QK(k3h, (f16)aq[rt][nt][r])
    STAGE_QK(k3l, (f16)(aq[rt][nt][r] - (float)(f16)aq[rt][nt][r]))
  }
}

// ---------------- K234: fused scores + top-64/softmax + PV -----------------
// 512 threads (8 waves), 16 t2-rows x full 1024 cols of one m. S in LDS fp32
// (stride 1028), 65.8 KB -> 2 blocks/CU = 16 waves/CU. Phase 1 uses explicit
// register staging (qh/ql all 8 upfront; B-frags in batches of 4) so 8+ loads
// are in flight per wave (round-6 VGPR=52 showed load serialization).
__global__ __launch_bounds__(512, 4) void k234_attn(
    const f16* __restrict__ q3h, const f16* __restrict__ q3l,
    const f16* __restrict__ k3h, const f16* __restrict__ k3l,
    const f16* __restrict__ v3T, f16* __restrict__ A) {
  __shared__ float S[16 * 1028];  // 65,792 B
  const int tid = threadIdx.x;
  const int w = tid >> 6, lane = tid & 63;
  const int quad = lane >> 4, lo = lane & 15;
  const int m = blockIdx.y;
  const int r0 = blockIdx.x * 16;  // t2-row tile

  // ---- phase 1: S = Q3 @ K3^T (split-f16, fp32 acc); wave w -> 128 cols ---
  {
    f32x4 acc[8];
#pragma unroll
    for (int i = 0; i < 8; ++i)
#pragma unroll
      for (int r = 0; r < 4; ++r) acc[i][r] = 0.f;

    const int64_t qoff = ((int64_t)m * 1024 + r0 + lo) * 128;
    f16x8 qh[4], ql[4];
#pragma unroll
    for (int kk = 0; kk < 4; ++kk) {
      const int koff = kk * 32 + quad * 8;
      qh[kk] = ldfrag(q3h + qoff + koff);
      ql[kk] = ldfrag(q3l + qoff + koff);
    }

#pragma unroll
    for (int kk = 0; kk < 4; ++kk) {
      const int koff = kk * 32 + quad * 8;
#pragma unroll
      for (int h2 = 0; h2 < 2; ++h2) {
        f16x8 bh[4], bl[4];
#pragma unroll
        for (int n4 = 0; n4 < 4; ++n4) {
          const int col = w * 128 + (h2 * 4 + n4) * 16 + lo;
          const int64_t bi = ((int64_t)m * 1024 + col) * 128 + koff;
          bh[n4] = ldfrag(k3h + bi);
          bl[n4] = ldfrag(k3l + bi);
        }
#pragma unroll
        for (int n4 = 0; n4 < 4; ++n4) {
          const int a = h2 * 4 + n4;
          acc[a] = MFMA16(qh[kk], bh[n4], acc[a]);
          acc[a] = MFMA16(qh[kk], bl[n4], acc[a]);
          acc[a] = MFMA16(ql[kk], bh[n4], acc[a]);
        }
      }
    }
#pragma unroll
    for (int nt = 0; nt < 8; ++nt)
#pragma unroll
      for (int r = 0; r < 4; ++r)
        S[(quad * 4 + r) * 1028 + w * 128 + nt * 16 + lo] = acc[nt][r];
  }
  __syncthreads();

  // ---- phase 2: exact fp32 top-64 + rowmin + causal + softmax -> f16 P ----
  // wave w owns rows {2w, 2w+1}; searches interleaved; float4 LDS access.
  // element s(i,e) = i*256 + lane*4 + e
  {
    const int row0 = w * 2;
    unsigned key[2][16];
    unsigned kmn0 = 0xFFFFFFFFu, kmn1 = 0xFFFFFFFFu;
    const float4* r4a = (const float4*)(S + row0 * 1028);
    const float4* r4b = (const float4*)(S + (row0 + 1) * 1028);
#pragma unroll
    for (int i = 0; i < 4; ++i) {
      const float4 fa = r4a[i * 64 + lane];
      const float4 fb = r4b[i * 64 + lane];
      const float fea[4] = {fa.x, fa.y, fa.z, fa.w};
      const float feb[4] = {fb.x, fb.y, fb.z, fb.w};
#pragma unroll
      for (int e = 0; e < 4; ++e) {
        const unsigned u0 = __builtin_bit_cast(unsigned, fea[e]);
        const unsigned u1 = __builtin_bit_cast(unsigned, feb[e]);
        const unsigned k0v = (u0 & 0x80000000u) ? ~u0 : (u0 | 0x80000000u);
        const unsigned k1v = (u1 & 0x80000000u) ? ~u1 : (u1 | 0x80000000u);
        key[0][i * 4 + e] = k0v; key[1][i * 4 + e] = k1v;
        kmn0 = min(kmn0, k0v); kmn1 = min(kmn1, k1v);
      }
    }
#pragma unroll
    for (int off = 32; off; off >>= 1) {
      kmn0 = min(kmn0, (unsigned)__shfl_xor((int)kmn0, off));
      kmn1 = min(kmn1, (unsigned)__shfl_xor((int)kmn1, off));
    }

    // bit-by-bit max T with count(key >= T) >= 64 (exact 64th-largest key)
    unsigned th0 = 0u, th1 = 0u;
    for (int b = 31; b >= 0; --b) {
      const unsigned c0 = th0 | (1u << b);
      const unsigned c1 = th1 | (1u << b);
      int cnt0 = 0, cnt1 = 0;
#pragma unroll
      for (int i = 0; i < 16; ++i) {
        cnt0 += (int)__popcll(__ballot(key[0][i] >= c0));
        cnt1 += (int)__popcll(__ballot(key[1][i] >= c1));
      }
      if (cnt0 >= 64) th0 = c0;
      if (cnt1 >= 64) th1 = c1;
    }

#pragma unroll
    for (int rr = 0; rr < 2; ++rr) {
      const unsigned kth = rr ? th1 : th0;
      const unsigned kmn = rr ? kmn1 : kmn0;
      const int row = row0 + rr, t2 = r0 + row;
      const unsigned umn = (kmn & 0x80000000u) ? (kmn ^ 0x80000000u) : ~kmn;
      const float mn = __builtin_bit_cast(float, umn);   // exact row min
      const unsigned ukv = (kth & 0x80000000u) ? (kth ^ 0x80000000u) : ~kth;
      const float kv = __builtin_bit_cast(float, ukv);   // 64th-largest value

      float ev[16];
      float sum = 0.f;
#pragma unroll
      for (int i = 0; i < 16; ++i) {
        const int s = (i >> 2) * 256 + lane * 4 + (i & 3);
        const unsigned k = key[rr][i];
        const unsigned uu = (k & 0x80000000u) ? (k ^ 0x80000000u) : ~k;
        const float f = __builtin_bit_cast(float, uu);
        const float ww = (k >= kth) ? f : mn;
        const float x = (s <= t2) ? __expf(ww - kv) : 0.f;  // kv-stabilized
        ev[i] = x;
        sum += x;
      }
      for (int off = 32; off; off >>= 1) sum += __shfl_xor(sum, off);
      const float inv = 1.0f / sum;

      f16* prow = (f16*)S + row * 2056;  // in-place over this row's fp32
#pragma unroll
      for (int i = 0; i < 4; ++i) {
        f16x4 pk;
#pragma unroll
        for (int e = 0; e < 4; ++e) pk[e] = (f16)(ev[i * 4 + e] * inv);
        ((f16x4*)prow)[i * 64 + lane] = pk;
      }
    }
  }
  __syncthreads();

  // ---- phase 3: A-tile = P @ V (K = 1024); wave w -> 16 kc cols, staged ---
  {
    const f16* P16 = (const f16*)S;
    f32x4 oacc;
#pragma unroll
    for (int r = 0; r < 4; ++r) oacc[r] = 0.f;
    const int kc = w * 16 + lo;
    const f16* vb = v3T + ((int64_t)m * 128 + kc) * 1024;
#pragma unroll
    for (int kb = 0; kb < 8; ++kb) {
      f16x8 vr[4];
#pragma unroll
      for (int u = 0; u < 4; ++u)
        vr[u] = ldfrag(vb + (kb * 4 + u) * 32 + quad * 8);
#pragma unroll
      for (int u = 0; u < 4; ++u) {
        const int k0 = (kb * 4 + u) * 32 + quad * 8;
        f16x8 a = *(const f16x8*)(P16 + lo * 2056 + k0);
        oacc = MFMA16(a, vr[u], oacc);
      }
    }
#pragma unroll
    for (int r = 0; r < 4; ++r) {
      const int row = r0 + quad * 4 + r;
      A[((int64_t)m * 1024 + row) * 128 + kc] = (f16)oacc[r];
    }
  }
}

// ---------------- K5: gather + output projection + bias --------------------
// 256 blocks x 256 thr; block = 32 rows; waves split (row-tile x col-half).
__global__ __launch_bounds__(256) void k5_proj(
    const f16* __restrict__ A, const f16* __restrict__ Wub,
    const float* __restrict__ bu, float* __restrict__ out) {
  const int w = threadIdx.x >> 6, lane = threadIdx.x & 63;
  const int quad = lane >> 4, lo = lane & 15;
  const int rt = w & 1, ch = w >> 1;
  const int r0 = blockIdx.x * 32 + rt * 16;  // row in [0,8192) = b*1024 + t2
  const int r = r0 + lo;
  const int bI = r >> 10, t2 = r & 1023;

  f32x4 acc[4];
#pragma unroll
  for (int i = 0; i < 4; ++i)
#pragma unroll
    for (int rr = 0; rr < 4; ++rr) acc[i][rr] = 0.f;

#pragma unroll 2
  for (int kk = 0; kk < 32; ++kk) {
    const int o = kk * 32 + quad * 8;  // feature index 0..1023
    const int j = o >> 7, kc = o & 127;
    f16x8 a = ldfrag(A + (((int64_t)(bI * 8 + j) * 1024 + t2) * 128 + kc));
    f16x8 wb[4];
#pragma unroll
    for (int nt = 0; nt < 4; ++nt)
      wb[nt] = ldfrag(Wub + (int64_t)(ch * 64 + nt * 16 + lo) * 1024 + o);
#pragma unroll
    for (int nt = 0; nt < 4; ++nt) acc[nt] = MFMA16(a, wb[nt], acc[nt]);
  }
#pragma unroll
  for (int nt = 0; nt < 4; ++nt) {
    const int col = ch * 64 + nt * 16 + lo;
    const float bias = bu[col];
#pragma unroll
    for (int rr = 0; rr < 4; ++rr) {
      const int row = r0 + quad * 4 + rr;
      out[(int64_t)row * 128 + col] = acc[nt][rr] + bias;
    }
  }
}

// ---------------- launcher --------------------------------------------------
extern "C" void kernel_launch(void* const* d_in, const int* in_sizes, int n_in,
                              void* d_out, int out_size, void* d_ws, size_t ws_size,
                              hipStream_t stream) {
  const float* x  = (const float*)d_in[0];
  const float* Wq = (const float*)d_in[1];
  const float* bq = (const float*)d_in[2];
  const float* Wk = (const float*)d_in[3];
  const float* bk = (const float*)d_in[4];
  const float* Wv = (const float*)d_in[5];
  const float* bv = (const float*)d_in[6];
  const float* Wu = (const float*)d_in[7];
  const float* bu = (const float*)d_in[8];
  float* out = (float*)d_out;

  char* ws = (char*)d_ws;
  f16* xh  = (f16*)ws;  ws += 2097152;
  f16* xl  = (f16*)ws;  ws += 2097152;
  f16* Wqh = (f16*)ws;  ws += 1310720;
  f16* Wql = (f16*)ws;  ws += 1310720;
  f16* Wkh = (f16*)ws;  ws += 1310720;
  f16* Wkl = (f16*)ws;  ws += 1310720;
  f16* Wvb = (f16*)ws;  ws += 262144;
  f16* Wub = (f16*)ws;  ws += 262144;
  f16* q3h = (f16*)ws;  ws += 16777216;           // 64*1024*128 fp16
  f16* q3l = (f16*)ws;  ws += 16777216;
  f16* k3h = (f16*)ws;  ws += 16777216;
  f16* k3l = (f16*)ws;  ws += 16777216;
  f16* v3T = (f16*)ws;  ws += 16777216;
  f16* A   = (f16*)ws;  ws += 16777216;           // total ~105.5 MB

  // K0: repack (exactly 2621440 threads = 10240 * 256)
  k0_prep<<<10240, 256, 0, stream>>>(x, Wq, Wk, Wv, Wu,
                                     xh, xl, Wqh, Wql, Wkh, Wkl, Wvb, Wub);

  // K1: convs + scramble; (row-tile, ch-half, Q/K) blocks of 4 waves
  k1_conv<<<dim3(256, 2, 2), 256, 0, stream>>>(xh, xl, Wqh, Wql, Wkh, Wkl, Wvb,
                                               bq, bk, bv, q3h, q3l, k3h, k3l,
                                               v3T);

  // K234: fused scores + selection/softmax + PV, 512-thread blocks
  k234_attn<<<dim3(64, 64), 512, 0, stream>>>(q3h, q3l, k3h, k3l, v3T, A);

  // K5: projection (8192 rows / 32 per block)
  k5_proj<<<256, 256, 0, stream>>>(A, Wub, bu, out);

  (void)in_sizes; (void)n_in; (void)out_size; (void)ws_size;
}

// Round 8
// 618.154 us; speedup vs baseline: 1.7513x; 1.2435x over previous
//
#include <hip/hip_runtime.h>
#include <hip/hip_fp16.h>
#include <cstdint>

using f16 = _Float16;
typedef __attribute__((ext_vector_type(8))) _Float16 f16x8;
typedef __attribute__((ext_vector_type(4))) _Float16 f16x4;
typedef __attribute__((ext_vector_type(4))) float f32x4;

#define MFMA16(a, b, c) __builtin_amdgcn_mfma_f32_16x16x32_f16((a), (b), (c), 0, 0, 0)

__device__ __forceinline__ f16x8 ldfrag(const f16* p) { return *(const f16x8*)p; }

// async global->LDS DMA, 16 B per lane; lds dest = wave-uniform base + lane*16
__device__ __forceinline__ void dma16(const f16* g, f16* l) {
  __builtin_amdgcn_global_load_lds(
      (const __attribute__((address_space(1))) void*)g,
      (__attribute__((address_space(3))) void*)l, 16, 0, 0);
}

// Problem constants: B=8, T=1024, K=128, H=8 -> M = B*H = 64 scrambled batches.
static const int64_t NX = 1048576;   // x elements: 8*1024*128
static const int64_t NW = 655360;    // Wq/Wk elements: 1024*128*5
static const int64_t NV = 131072;    // Wv / Wu elements: 1024*128

// ---------------- K0: split-convert/repack weights and x to fp16 hi/lo -----
__global__ __launch_bounds__(256) void k0_prep(
    const float* __restrict__ x, const float* __restrict__ Wq,
    const float* __restrict__ Wk, const float* __restrict__ Wv,
    const float* __restrict__ Wu,
    f16* __restrict__ xh, f16* __restrict__ xl,
    f16* __restrict__ Wqh, f16* __restrict__ Wql,
    f16* __restrict__ Wkh, f16* __restrict__ Wkl,
    f16* __restrict__ Wvb, f16* __restrict__ Wub) {
  int64_t i = (int64_t)blockIdx.x * 256 + threadIdx.x;  // grid sized exactly
  if (i < NX) {
    const float v = x[i];
    const f16 h = (f16)v;
    xh[i] = h; xl[i] = (f16)(v - (float)h);
  } else if (i < NX + NW) {
    int64_t d = i - NX;
    int j = (int)(d >> 17);
    int rem = (int)(d & 131071);
    int o = rem >> 7, c = rem & 127;
    const float v = Wq[(int64_t)(o * 128 + c) * 5 + j];   // layout [j][o][c]
    const f16 h = (f16)v;
    Wqh[d] = h; Wql[d] = (f16)(v - (float)h);
  } else if (i < NX + 2 * NW) {
    int64_t d = i - NX - NW;
    int j = (int)(d >> 17);
    int rem = (int)(d & 131071);
    int o = rem >> 7, c = rem & 127;
    const float v = Wk[(int64_t)(o * 128 + c) * 5 + j];
    const f16 h = (f16)v;
    Wkh[d] = h; Wkl[d] = (f16)(v - (float)h);
  } else if (i < NX + 2 * NW + NV) {
    int64_t d = i - NX - 2 * NW;
    Wvb[d] = (f16)Wv[d];                                // [o][c]
  } else {
    int64_t d = i - NX - 2 * NW - NV;
    Wub[d] = (f16)Wu[d];                                // [c][o]
  }
}

// ---------------- K1: causal convs (split-f16) + LDS-staged coalesced out --
#define STAGE_QK(DST, VALEXPR)                                          \
  {                                                                     \
    __syncthreads();                                                    \
    _Pragma("unroll")                                                   \
    for (int nt = 0; nt < 8; ++nt) {                                    \
      const int o = o0 + nt * 16 + lo;                                  \
      const int kcl = (o >> 3) & 63, hh = o & 7;                        \
      _Pragma("unroll")                                                 \
      for (int rt = 0; rt < 2; ++rt) {                                  \
        _Pragma("unroll")                                               \
        for (int r = 0; r < 4; ++r) {                                   \
          const int t2l = (rt * 16 + quad * 4 + r) * 8 + hh;            \
          lds[t2l * 72 + kcl] = (VALEXPR);                              \
        }                                                               \
      }                                                                 \
    }                                                                   \
    __syncthreads();                                                    \
    _Pragma("unroll")                                                   \
    for (int p = 0; p < 8; ++p) {                                       \
      const int idx = p * 256 + tid;                                    \
      const int a = idx >> 3, c8 = (idx & 7) * 8;                       \
      *(f16x8*)(DST + ((int64_t)m * 1024 + t2b + a) * 128 +             \
                half * 64 + c8) = *(const f16x8*)&lds[a * 72 + c8];     \
    }                                                                   \
  }

__global__ __launch_bounds__(256) void k1_conv(
    const f16* __restrict__ xh, const f16* __restrict__ xl,
    const f16* __restrict__ Wqh, const f16* __restrict__ Wql,
    const f16* __restrict__ Wkh, const f16* __restrict__ Wkl,
    const f16* __restrict__ Wvb,
    const float* __restrict__ bq, const float* __restrict__ bk,
    const float* __restrict__ bv,
    f16* __restrict__ q3h, f16* __restrict__ q3l,
    f16* __restrict__ k3h, f16* __restrict__ k3l,
    f16* __restrict__ v3T) {
  __shared__ f16 lds[18432];  // max(256*72, 64*264) elems = 36.9 KB
  const int tid = threadIdx.x;
  const int w = tid >> 6, lane = tid & 63;
  const int quad = lane >> 4, lo = lane & 15;
  const int r0 = blockIdx.x * 32;     // rows r0..r0+31 (same b, same m)
  const int bb = r0 >> 10;
  const int m  = r0 >> 7;
  const int t2b = (r0 & 127) * 8;
  const int half = blockIdx.y;        // which 512-channel half
  const int isK = blockIdx.z;         // 0 = Q (+V), 1 = K
  const int o0 = half * 512 + w * 128;

  const f16* Wh = isK ? Wkh : Wqh;
  const f16* Wl = isK ? Wkl : Wql;
  const float* bias = isK ? bk : bq;

  // ---- V pass (Q-blocks only): 1 tap, hi only ----
  if (!isK) {
    f32x4 av[2][8];
#pragma unroll
    for (int rt = 0; rt < 2; ++rt)
#pragma unroll
      for (int i = 0; i < 8; ++i)
#pragma unroll
        for (int r = 0; r < 4; ++r) av[rt][i][r] = 0.f;

#pragma unroll
    for (int kk = 0; kk < 4; ++kk) {
      const int koff = kk * 32 + quad * 8;
      f16x8 ah[2];
#pragma unroll
      for (int rt = 0; rt < 2; ++rt) {
        const int tt = (r0 + rt * 16 + lo) & 1023;
        ah[rt] = ldfrag(xh + ((int64_t)(bb * 1024 + tt)) * 128 + koff);
      }
#pragma unroll
      for (int nt = 0; nt < 8; ++nt) {
        const int n = o0 + nt * 16 + lo;
        f16x8 bv8 = ldfrag(Wvb + (int64_t)n * 128 + koff);
        av[0][nt] = MFMA16(ah[0], bv8, av[0][nt]);
        av[1][nt] = MFMA16(ah[1], bv8, av[1][nt]);
      }
    }
#pragma unroll
    for (int nt = 0; nt < 8; ++nt) {
      const int o = o0 + nt * 16 + lo;
      const float vbv = bv[o];
      const int kcl = (o >> 3) & 63, hh = o & 7;
#pragma unroll
      for (int rt = 0; rt < 2; ++rt)
#pragma unroll
        for (int r = 0; r < 4; ++r) {
          const int t2l = (rt * 16 + quad * 4 + r) * 8 + hh;
          lds[kcl * 264 + t2l] = (f16)(av[rt][nt][r] + vbv);
        }
    }
    __syncthreads();
#pragma unroll
    for (int p = 0; p < 8; ++p) {
      const int idx = p * 256 + tid;
      const int kcl = idx >> 5, t8 = (idx & 31) * 8;
      *(f16x8*)(v3T + ((int64_t)m * 128 + half * 64 + kcl) * 1024 + t2b + t8) =
          *(const f16x8*)&lds[kcl * 264 + t8];
    }
  }

  // ---- Q or K main loop: 5 taps, split-f16 (3 MFMAs per tap) ----
  f32x4 aq[2][8];
#pragma unroll
  for (int rt = 0; rt < 2; ++rt)
#pragma unroll
    for (int i = 0; i < 8; ++i)
#pragma unroll
      for (int r = 0; r < 4; ++r) aq[rt][i][r] = 0.f;

#pragma unroll
  for (int j = 0; j < 5; ++j) {
    bool ok[2]; int64_t xoff[2];
#pragma unroll
    for (int rt = 0; rt < 2; ++rt) {
      const int tt = (r0 + rt * 16 + lo) & 1023;
      const int tp = tt + j - 4;            // causal left-pad 4
      ok[rt] = (tp >= 0);
      xoff[rt] = ((int64_t)(bb * 1024 + (ok[rt] ? tp : 0))) * 128;
    }
#pragma unroll
    for (int kk = 0; kk < 4; ++kk) {
      const int koff = kk * 32 + quad * 8;
      f16x8 ah[2], al[2];
#pragma unroll
      for (int rt = 0; rt < 2; ++rt) {
        ah[rt] = ldfrag(xh + xoff[rt] + koff);
        al[rt] = ldfrag(xl + xoff[rt] + koff);
        if (!ok[rt]) {
#pragma unroll
          for (int e = 0; e < 8; ++e) { ah[rt][e] = (f16)0; al[rt][e] = (f16)0; }
        }
      }
#pragma unroll
      for (int nt = 0; nt < 8; ++nt) {
        const int n = o0 + nt * 16 + lo;
        const int64_t wi = (int64_t)j * 131072 + (int64_t)n * 128 + koff;
        f16x8 bh = ldfrag(Wh + wi);
        f16x8 bl = ldfrag(Wl + wi);
#pragma unroll
        for (int rt = 0; rt < 2; ++rt) {
          aq[rt][nt] = MFMA16(ah[rt], bh, aq[rt][nt]);
          aq[rt][nt] = MFMA16(ah[rt], bl, aq[rt][nt]);
          aq[rt][nt] = MFMA16(al[rt], bh, aq[rt][nt]);
        }
      }
    }
  }

  const float SC = 0.29730177875068026f;  // 128^-0.25
#pragma unroll
  for (int nt = 0; nt < 8; ++nt) {
    const int o = o0 + nt * 16 + lo;
    const float vb = bias[o];
#pragma unroll
    for (int rt = 0; rt < 2; ++rt)
#pragma unroll
      for (int r = 0; r < 4; ++r) aq[rt][nt][r] = (aq[rt][nt][r] + vb) * SC;
  }

  if (!isK) {
    STAGE_QK(q3h, (f16)aq[rt][nt][r])
    STAGE_QK(q3l, (f16)(aq[rt][nt][r] - (float)(f16)aq[rt][nt][r]))
  } else {
    STAGE_QK(k3h, (f16)aq[rt][nt][r])
    STAGE_QK(k3l, (f16)(aq[rt][nt][r] - (float)(f16)aq[rt][nt][r]))
  }
}

// ---------------- K234: DMA-streamed scores + top-64/softmax + PV ----------
// 512 thr (8 waves), 16 rows x 1024 cols of one m. K/V tiles stream
// global->LDS via global_load_lds into per-wave-owned slots (1 barrier per
// chunk provides the vmcnt drain). S materialized 512 cols at a time
// (16x516 fp32, 33 KB); keys snapshotted to registers between halves;
// selection/softmax unchanged; P in place over S (f16, stride 1032).
// LDS total 65.8 KB -> 2 blocks/CU.
__global__ __launch_bounds__(512, 4) void k234_attn(
    const f16* __restrict__ q3h, const f16* __restrict__ q3l,
    const f16* __restrict__ k3h, const f16* __restrict__ k3l,
    const f16* __restrict__ v3T, f16* __restrict__ A) {
  __shared__ float Sb[16 * 516];   // 33,024 B: S fp32 half / P f16 full
  __shared__ f16 kbuf[16384];      // 32,768 B: 32 DMA slots x 512 f16
  const int tid = threadIdx.x;
  const int w = tid >> 6, lane = tid & 63;
  const int quad = lane >> 4, lo = lane & 15;
  const int qd = lane & 3, cit = lane >> 2;  // DMA lane decomposition
  const int m = blockIdx.y;
  const int r0 = blockIdx.x * 16;

  // Q fragments (A-operand) for rows r0..r0+15, all K
  const int64_t qoff = ((int64_t)m * 1024 + r0 + lo) * 128;
  f16x8 qh[4], ql[4];
#pragma unroll
  for (int kk = 0; kk < 4; ++kk) {
    qh[kk] = ldfrag(q3h + qoff + kk * 32 + quad * 8);
    ql[kk] = ldfrag(q3l + qoff + kk * 32 + quad * 8);
  }

  unsigned key[2][16];
  unsigned kmn0 = 0xFFFFFFFFu, kmn1 = 0xFFFFFFFFu;

  // ---- phase 1: S = Q @ K^T, streamed; wave w owns col-tile w per chunk ---
#pragma unroll
  for (int half = 0; half < 2; ++half) {
    f32x4 acc[4];
#pragma unroll
    for (int i = 0; i < 4; ++i)
#pragma unroll
      for (int r = 0; r < 4; ++r) acc[i][r] = 0.f;

    for (int kp = 0; kp < 2; ++kp) {      // 64-K span (full 128B lines)
#pragma unroll
      for (int cc = 0; cc < 4; ++cc) {    // 128-col chunk
        const int c0 = half * 512 + cc * 128;
        const int64_t rowg = (int64_t)(m * 1024 + c0 + w * 16 + cit) * 128;
        // 4 DMA issues into this wave's 4 slots: (tensor t, K-half kkh)
#pragma unroll
        for (int t = 0; t < 2; ++t) {
          const f16* srcb = t ? k3l : k3h;
#pragma unroll
          for (int kkh = 0; kkh < 2; ++kkh)
            dma16(srcb + rowg + (kp * 2 + kkh) * 32 + qd * 8,
                  kbuf + (w * 4 + t * 2 + kkh) * 512);
        }
        __syncthreads();  // drains DMA (vmcnt 0) + sync
#pragma unroll
        for (int kkh = 0; kkh < 2; ++kkh) {
          const int kkg = kp * 2 + kkh;
          f16x8 bh = *(const f16x8*)(kbuf + (w * 4 + kkh) * 512 +
                                     (lo * 4 + quad) * 8);
          f16x8 bl = *(const f16x8*)(kbuf + (w * 4 + 2 + kkh) * 512 +
                                     (lo * 4 + quad) * 8);
          acc[cc] = MFMA16(qh[kkg], bh, acc[cc]);
          acc[cc] = MFMA16(qh[kkg], bl, acc[cc]);
          acc[cc] = MFMA16(ql[kkg], bh, acc[cc]);
        }
      }
    }
    // write S half (cols half*512 .. +511)
#pragma unroll
    for (int cc = 0; cc < 4; ++cc)
#pragma unroll
      for (int r = 0; r < 4; ++r)
        Sb[(quad * 4 + r) * 516 + cc * 128 + w * 16 + lo] = acc[cc][r];
    __syncthreads();
    // snapshot keys: wave w owns rows 2w, 2w+1
#pragma unroll
    for (int rr = 0; rr < 2; ++rr) {
      const float4* rp = (const float4*)(Sb + (w * 2 + rr) * 516);
#pragma unroll
      for (int i2 = 0; i2 < 2; ++i2) {
        const float4 f4 = rp[i2 * 64 + lane];
        const float fe[4] = {f4.x, f4.y, f4.z, f4.w};
#pragma unroll
        for (int e = 0; e < 4; ++e) {
          const unsigned u = __builtin_bit_cast(unsigned, fe[e]);
          const unsigned k = (u & 0x80000000u) ? ~u : (u | 0x80000000u);
          key[rr][half * 8 + i2 * 4 + e] = k;
          if (rr == 0) kmn0 = min(kmn0, k); else kmn1 = min(kmn1, k);
        }
      }
    }
    __syncthreads();  // all key reads done before next half overwrites S
  }

  // ---- phase 2: exact fp32 top-64 + rowmin + causal + softmax -> P --------
  f16* P16 = (f16*)Sb;  // row stride 1032 f16 (= 516 f32)
  {
#pragma unroll
    for (int off = 32; off; off >>= 1) {
      kmn0 = min(kmn0, (unsigned)__shfl_xor((int)kmn0, off));
      kmn1 = min(kmn1, (unsigned)__shfl_xor((int)kmn1, off));
    }
    unsigned th0 = 0u, th1 = 0u;
    for (int b = 31; b >= 0; --b) {
      const unsigned c0 = th0 | (1u << b);
      const unsigned c1 = th1 | (1u << b);
      int cnt0 = 0, cnt1 = 0;
#pragma unroll
      for (int i = 0; i < 16; ++i) {
        cnt0 += (int)__popcll(__ballot(key[0][i] >= c0));
        cnt1 += (int)__popcll(__ballot(key[1][i] >= c1));
      }
      if (cnt0 >= 64) th0 = c0;
      if (cnt1 >= 64) th1 = c1;
    }

#pragma unroll
    for (int rr = 0; rr < 2; ++rr) {
      const unsigned kth = rr ? th1 : th0;
      const unsigned kmn = rr ? kmn1 : kmn0;
      const int row = w * 2 + rr, t2 = r0 + row;
      const unsigned umn = (kmn & 0x80000000u) ? (kmn ^ 0x80000000u) : ~kmn;
      const float mn = __builtin_bit_cast(float, umn);   // exact row min
      const unsigned ukv = (kth & 0x80000000u) ? (kth ^ 0x80000000u) : ~kth;
      const float kv = __builtin_bit_cast(float, ukv);   // 64th-largest value

      float ev[16];
      float sum = 0.f;
#pragma unroll
      for (int j = 0; j < 16; ++j) {
        const int s = (j >> 3) * 512 + ((j >> 2) & 1) * 256 + lane * 4 + (j & 3);
        const unsigned k = key[rr][j];
        const unsigned uu = (k & 0x80000000u) ? (k ^ 0x80000000u) : ~k;
        const float f = __builtin_bit_cast(float, uu);
        const float ww = (k >= kth) ? f : mn;
        const float x = (s <= t2) ? __expf(ww - kv) : 0.f;  // kv-stabilized
        ev[j] = x;
        sum += x;
      }
      for (int off = 32; off; off >>= 1) sum += __shfl_xor(sum, off);
      const float inv = 1.0f / sum;

      f16* prow = P16 + row * 1032;  // in place over this row's S
#pragma unroll
      for (int hh = 0; hh < 2; ++hh)
#pragma unroll
        for (int i2 = 0; i2 < 2; ++i2) {
          f16x4 pk;
#pragma unroll
          for (int e = 0; e < 4; ++e)
            pk[e] = (f16)(ev[hh * 8 + i2 * 4 + e] * inv);
          *(f16x4*)(prow + hh * 512 + i2 * 256 + lane * 4) = pk;
        }
    }
  }
  __syncthreads();  // P visible to all; kbuf slot remap safe

  // ---- phase 3: A = P @ V, v3T streamed; wave w -> kc = w*16..+15 ---------
  {
    f32x4 oacc;
#pragma unroll
    for (int r = 0; r < 4; ++r) oacc[r] = 0.f;
    const int64_t vrow = (int64_t)(m * 128 + w * 16 + cit) * 1024;
    for (int kb = 0; kb < 16; ++kb) {   // 64-K spans
#pragma unroll
      for (int kkh = 0; kkh < 2; ++kkh)
        dma16(v3T + vrow + kb * 64 + kkh * 32 + qd * 8,
              kbuf + (w * 2 + kkh) * 512);
      __syncthreads();
#pragma unroll
      for (int kkh = 0; kkh < 2; ++kkh) {
        f16x8 vf = *(const f16x8*)(kbuf + (w * 2 + kkh) * 512 +
                                   (lo * 4 + quad) * 8);
        f16x8 af = *(const f16x8*)(P16 + lo * 1032 + kb * 64 + kkh * 32 +
                                   quad * 8);
        oacc = MFMA16(af, vf, oacc);
      }
    }
#pragma unroll
    for (int r = 0; r < 4; ++r)
      A[((int64_t)m * 1024 + r0 + quad * 4 + r) * 128 + w * 16 + lo] =
          (f16)oacc[r];
  }
}

// ---------------- K5: gather + output projection + bias --------------------
__global__ __launch_bounds__(256) void k5_proj(
    const f16* __restrict__ A, const f16* __restrict__ Wub,
    const float* __restrict__ bu, float* __restrict__ out) {
  const int w = threadIdx.x >> 6, lane = threadIdx.x & 63;
  const int quad = lane >> 4, lo = lane & 15;
  const int rt = w & 1, ch = w >> 1;
  const int r0 = blockIdx.x * 32 + rt * 16;  // row in [0,8192) = b*1024 + t2
  const int r = r0 + lo;
  const int bI = r >> 10, t2 = r & 1023;

  f32x4 acc[4];
#pragma unroll
  for (int i = 0; i < 4; ++i)
#pragma unroll
    for (int rr = 0; rr < 4; ++rr) acc[i][rr] = 0.f;

#pragma unroll 2
  for (int kk = 0; kk < 32; ++kk) {
    const int o = kk * 32 + quad * 8;  // feature index 0..1023
    const int j = o >> 7, kc = o & 127;
    f16x8 a = ldfrag(A + (((int64_t)(bI * 8 + j) * 1024 + t2) * 128 + kc));
    f16x8 wb[4];
#pragma unroll
    for (int nt = 0; nt < 4; ++nt)
      wb[nt] = ldfrag(Wub + (int64_t)(ch * 64 + nt * 16 + lo) * 1024 + o);
#pragma unroll
    for (int nt = 0; nt < 4; ++nt) acc[nt] = MFMA16(a, wb[nt], acc[nt]);
  }
#pragma unroll
  for (int nt = 0; nt < 4; ++nt) {
    const int col = ch * 64 + nt * 16 + lo;
    const float bias = bu[col];
#pragma unroll
    for (int rr = 0; rr < 4; ++rr) {
      const int row = r0 + quad * 4 + rr;
      out[(int64_t)row * 128 + col] = acc[nt][rr] + bias;
    }
  }
}

// ---------------- launcher --------------------------------------------------
extern "C" void kernel_launch(void* const* d_in, const int* in_sizes, int n_in,
                              void* d_out, int out_size, void* d_ws, size_t ws_size,
                              hipStream_t stream) {
  const float* x  = (const float*)d_in[0];
  const float* Wq = (const float*)d_in[1];
  const float* bq = (const float*)d_in[2];
  const float* Wk = (const float*)d_in[3];
  const float* bk = (const float*)d_in[4];
  const float* Wv = (const float*)d_in[5];
  const float* bv = (const float*)d_in[6];
  const float* Wu = (const float*)d_in[7];
  const float* bu = (const float*)d_in[8];
  float* out = (float*)d_out;

  char* ws = (char*)d_ws;
  f16* xh  = (f16*)ws;  ws += 2097152;
  f16* xl  = (f16*)ws;  ws += 2097152;
  f16* Wqh = (f16*)ws;  ws += 1310720;
  f16* Wql = (f16*)ws;  ws += 1310720;
  f16* Wkh = (f16*)ws;  ws += 1310720;
  f16* Wkl = (f16*)ws;  ws += 1310720;
  f16* Wvb = (f16*)ws;  ws += 262144;
  f16* Wub = (f16*)ws;  ws += 262144;
  f16* q3h = (f16*)ws;  ws += 16777216;           // 64*1024*128 fp16
  f16* q3l = (f16*)ws;  ws += 16777216;
  f16* k3h = (f16*)ws;  ws += 16777216;
  f16* k3l = (f16*)ws;  ws += 16777216;
  f16* v3T = (f16*)ws;  ws += 16777216;
  f16* A   = (f16*)ws;  ws += 16777216;           // total ~105.5 MB

  // K0: repack (exactly 2621440 threads = 10240 * 256)
  k0_prep<<<10240, 256, 0, stream>>>(x, Wq, Wk, Wv, Wu,
                                     xh, xl, Wqh, Wql, Wkh, Wkl, Wvb, Wub);

  // K1: convs + scramble; (row-tile, ch-half, Q/K) blocks of 4 waves
  k1_conv<<<dim3(256, 2, 2), 256, 0, stream>>>(xh, xl, Wqh, Wql, Wkh, Wkl, Wvb,
                                               bq, bk, bv, q3h, q3l, k3h, k3l,
                                               v3T);

  // K234: DMA-streamed fused attention
  k234_attn<<<dim3(64, 64), 512, 0, stream>>>(q3h, q3l, k3h, k3l, v3T, A);

  // K5: projection (8192 rows / 32 per block)
  k5_proj<<<256, 256, 0, stream>>>(A, Wub, bu, out);

  (void)in_sizes; (void)n_in; (void)out_size; (void)ws_size;
}

// Round 10
// 535.594 us; speedup vs baseline: 2.0213x; 1.1541x over previous
//
#include <hip/hip_runtime.h>
#include <hip/hip_fp16.h>
#include <cstdint>

using f16 = _Float16;
typedef __attribute__((ext_vector_type(8))) _Float16 f16x8;
typedef __attribute__((ext_vector_type(4))) _Float16 f16x4;
typedef __attribute__((ext_vector_type(4))) float f32x4;

#define MFMA16(a, b, c) __builtin_amdgcn_mfma_f32_16x16x32_f16((a), (b), (c), 0, 0, 0)

__device__ __forceinline__ f16x8 ldfrag(const f16* p) { return *(const f16x8*)p; }

// async global->LDS DMA, 16 B per lane; lds dest = wave-uniform base + lane*16
__device__ __forceinline__ void dma16(const f16* g, f16* l) {
  __builtin_amdgcn_global_load_lds(
      (const __attribute__((address_space(1))) void*)g,
      (__attribute__((address_space(3))) void*)l, 16, 0, 0);
}
// explicit per-wave fences (do NOT rely on compiler LDS-DMA modeling):
// drain own DMA before reading own slots; drain own ds_reads before next DMA
// can overwrite the slot.
__device__ __forceinline__ void wait_vm0() {
  asm volatile("s_waitcnt vmcnt(0)" ::: "memory");
}
__device__ __forceinline__ void wait_lgkm0() {
  asm volatile("s_waitcnt lgkmcnt(0)" ::: "memory");
}

// Problem constants: B=8, T=1024, K=128, H=8 -> M = B*H = 64 scrambled batches.
static const int64_t NX = 1048576;   // x elements: 8*1024*128
static const int64_t NW = 655360;    // Wq/Wk elements: 1024*128*5
static const int64_t NV = 131072;    // Wv / Wu elements: 1024*128

// ---------------- K0: split-convert/repack weights and x to fp16 hi/lo -----
__global__ __launch_bounds__(256) void k0_prep(
    const float* __restrict__ x, const float* __restrict__ Wq,
    const float* __restrict__ Wk, const float* __restrict__ Wv,
    const float* __restrict__ Wu,
    f16* __restrict__ xh, f16* __restrict__ xl,
    f16* __restrict__ Wqh, f16* __restrict__ Wql,
    f16* __restrict__ Wkh, f16* __restrict__ Wkl,
    f16* __restrict__ Wvb, f16* __restrict__ Wub) {
  int64_t i = (int64_t)blockIdx.x * 256 + threadIdx.x;  // grid sized exactly
  if (i < NX) {
    const float v = x[i];
    const f16 h = (f16)v;
    xh[i] = h; xl[i] = (f16)(v - (float)h);
  } else if (i < NX + NW) {
    int64_t d = i - NX;
    int j = (int)(d >> 17);
    int rem = (int)(d & 131071);
    int o = rem >> 7, c = rem & 127;
    const float v = Wq[(int64_t)(o * 128 + c) * 5 + j];   // layout [j][o][c]
    const f16 h = (f16)v;
    Wqh[d] = h; Wql[d] = (f16)(v - (float)h);
  } else if (i < NX + 2 * NW) {
    int64_t d = i - NX - NW;
    int j = (int)(d >> 17);
    int rem = (int)(d & 131071);
    int o = rem >> 7, c = rem & 127;
    const float v = Wk[(int64_t)(o * 128 + c) * 5 + j];
    const f16 h = (f16)v;
    Wkh[d] = h; Wkl[d] = (f16)(v - (float)h);
  } else if (i < NX + 2 * NW + NV) {
    int64_t d = i - NX - 2 * NW;
    Wvb[d] = (f16)Wv[d];                                // [o][c]
  } else {
    int64_t d = i - NX - 2 * NW - NV;
    Wub[d] = (f16)Wu[d];                                // [c][o]
  }
}

// ---------------- K1: causal convs, DMA-streamed weights + LDS x -----------
// Wave-private wbuf slots [w*4096, +4096): stream loops are barrier-free
// (per-wave vmcnt/lgkmcnt fences). Barriers only around cross-wave staging.
#define STAGE_QK(DST, VALEXPR)                                          \
  {                                                                     \
    __syncthreads();                                                    \
    _Pragma("unroll")                                                   \
    for (int nt = 0; nt < 8; ++nt) {                                    \
      const int o = o0 + nt * 16 + lo;                                  \
      const int kcl = (o >> 3) & 63, hh = o & 7;                        \
      _Pragma("unroll")                                                 \
      for (int rt = 0; rt < 2; ++rt) {                                  \
        _Pragma("unroll")                                               \
        for (int r = 0; r < 4; ++r) {                                   \
          const int t2l = (rt * 16 + quad * 4 + r) * 8 + hh;            \
          lds[t2l * 72 + kcl] = (VALEXPR);                              \
        }                                                               \
      }                                                                 \
    }                                                                   \
    __syncthreads();                                                    \
    _Pragma("unroll")                                                   \
    for (int p = 0; p < 8; ++p) {                                       \
      const int idx = p * 256 + tid;                                    \
      const int a = idx >> 3, c8 = (idx & 7) * 8;                       \
      *(f16x8*)(DST + ((int64_t)m * 1024 + t2b + a) * 128 +             \
                half * 64 + c8) = *(const f16x8*)&lds[a * 72 + c8];     \
    }                                                                   \
  }

__global__ __launch_bounds__(256) void k1_conv(
    const f16* __restrict__ xh, const f16* __restrict__ xl,
    const f16* __restrict__ Wqh, const f16* __restrict__ Wql,
    const f16* __restrict__ Wkh, const f16* __restrict__ Wkl,
    const f16* __restrict__ Wvb,
    const float* __restrict__ bq, const float* __restrict__ bk,
    const float* __restrict__ bv,
    f16* __restrict__ q3h, f16* __restrict__ q3l,
    f16* __restrict__ k3h, f16* __restrict__ k3l,
    f16* __restrict__ v3T) {
  __shared__ f16 shm[27936];      // 55.9 KB: [0,18432) wbuf/stage, rest xbuf
  f16* const wbuf = shm;
  f16* const xbuf = shm + 18432;
  f16* const lds  = shm;          // staging alias
  const int tid = threadIdx.x;
  const int w = tid >> 6, lane = tid & 63;
  const int quad = lane >> 4, lo = lane & 15;
  const int r0 = blockIdx.x * 32;     // rows r0..r0+31 (same b, same m)
  const int bb = r0 >> 10;
  const int m  = r0 >> 7;
  const int t2b = (r0 & 127) * 8;
  const int tloc = r0 & 1023;
  const int half = blockIdx.y;        // which 512-channel half
  const int isK = blockIdx.z;         // 0 = Q (+V), 1 = K
  const int o0 = half * 512 + w * 128;

  const f16* Wh = isK ? Wkh : Wqh;
  const f16* Wl = isK ? Wkl : Wql;
  const float* bias = isK ? bk : bq;

  // ---- stage x rows [tloc-4, tloc+32) (clamped at batch start) ----
#pragma unroll
  for (int p = 0; p < 5; ++p) {
    const int u = p * 256 + tid;           // f16x8 unit
    if (u < 1152) {
      const int row = u >> 5, tz = (u >> 4) & 1, c8 = (u & 15) * 8;
      int lt = tloc - 4 + row;
      if (lt < 0) lt = 0;
      const f16* src = (tz ? xl : xh) + ((int64_t)(bb * 1024 + lt)) * 128 + c8;
      *(f16x8*)&xbuf[row * 264 + tz * 128 + c8] = *(const f16x8*)src;
    }
  }
  __syncthreads();

  // per-lane gather offset within a 16n x 128c fragment block
  const int64_t wlane = (int64_t)(lane & 15) * 128 + (lane >> 4) * 8;

  // ---- V pass (Q-blocks only): pointwise tap, hi only; barrier-free ----
  if (!isK) {
    f32x4 av[2][8];
#pragma unroll
    for (int rt = 0; rt < 2; ++rt)
#pragma unroll
      for (int i = 0; i < 8; ++i)
#pragma unroll
        for (int r = 0; r < 4; ++r) av[rt][i][r] = 0.f;

#pragma unroll
    for (int g = 0; g < 4; ++g) {
#pragma unroll
      for (int s = 0; s < 2; ++s) {
        const int64_t vsrc = (int64_t)(o0 + (g * 2 + s) * 16) * 128 + wlane;
#pragma unroll
        for (int kk = 0; kk < 4; ++kk)
          dma16(Wvb + vsrc + kk * 32, wbuf + w * 4096 + s * 2048 + kk * 512);
      }
      wait_vm0();   // own DMA landed
#pragma unroll
      for (int kk = 0; kk < 4; ++kk) {
        const f16x8 a0 = *(const f16x8*)&xbuf[(lo + 4) * 264 + kk * 32 + quad * 8];
        const f16x8 a1 =
            *(const f16x8*)&xbuf[(16 + lo + 4) * 264 + kk * 32 + quad * 8];
#pragma unroll
        for (int s = 0; s < 2; ++s) {
          const f16x8 bv8 = *(const f16x8*)&wbuf[w * 4096 + s * 2048 + kk * 512 +
                                                 quad * 128 + lo * 8];
          av[0][g * 2 + s] = MFMA16(a0, bv8, av[0][g * 2 + s]);
          av[1][g * 2 + s] = MFMA16(a1, bv8, av[1][g * 2 + s]);
        }
      }
      wait_lgkm0();  // own ds_reads sampled before next DMA can land
    }
    __syncthreads();  // all waves done with wbuf before cross-wave staging
    // bias + stage v3T via LDS [kcl][t2l] (stride 264), coalesced out
#pragma unroll
    for (int nt = 0; nt < 8; ++nt) {
      const int o = o0 + nt * 16 + lo;
      const float vbv = bv[o];
      const int kcl = (o >> 3) & 63, hh = o & 7;
#pragma unroll
      for (int rt = 0; rt < 2; ++rt)
#pragma unroll
        for (int r = 0; r < 4; ++r) {
          const int t2l = (rt * 16 + quad * 4 + r) * 8 + hh;
          lds[kcl * 264 + t2l] = (f16)(av[rt][nt][r] + vbv);
        }
    }
    __syncthreads();
#pragma unroll
    for (int p = 0; p < 8; ++p) {
      const int idx = p * 256 + tid;
      const int kcl = idx >> 5, t8 = (idx & 31) * 8;
      *(f16x8*)(v3T + ((int64_t)m * 128 + half * 64 + kcl) * 1024 + t2b + t8) =
          *(const f16x8*)&lds[kcl * 264 + t8];
    }
    __syncthreads();  // staging reads done before QK stream reuses wbuf
  }

  // ---- Q or K main: 5 taps x 8 nt chunks, barrier-free stream ----
  f32x4 aq[2][8];
#pragma unroll
  for (int rt = 0; rt < 2; ++rt)
#pragma unroll
    for (int i = 0; i < 8; ++i)
#pragma unroll
      for (int r = 0; r < 4; ++r) { aq[rt][i][r] = 0.f; }

  for (int j = 0; j < 5; ++j) {
    const bool z0 = (tloc == 0);
#pragma unroll
    for (int nt = 0; nt < 8; ++nt) {
      const int64_t wsrc =
          (int64_t)j * 131072 + (int64_t)(o0 + nt * 16) * 128 + wlane;
#pragma unroll
      for (int kk = 0; kk < 4; ++kk) {
        dma16(Wh + wsrc + kk * 32, wbuf + w * 4096 + kk * 512);
        dma16(Wl + wsrc + kk * 32, wbuf + w * 4096 + 2048 + kk * 512);
      }
      wait_vm0();   // own DMA landed
#pragma unroll
      for (int kk = 0; kk < 4; ++kk) {
        const f16x8 bh =
            *(const f16x8*)&wbuf[w * 4096 + kk * 512 + quad * 128 + lo * 8];
        const f16x8 bl =
            *(const f16x8*)&wbuf[w * 4096 + 2048 + kk * 512 + quad * 128 + lo * 8];
        f16x8 ah0 = *(const f16x8*)&xbuf[(lo + j) * 264 + kk * 32 + quad * 8];
        f16x8 al0 =
            *(const f16x8*)&xbuf[(lo + j) * 264 + 128 + kk * 32 + quad * 8];
        const f16x8 ah1 =
            *(const f16x8*)&xbuf[(16 + lo + j) * 264 + kk * 32 + quad * 8];
        const f16x8 al1 =
            *(const f16x8*)&xbuf[(16 + lo + j) * 264 + 128 + kk * 32 + quad * 8];
        if (z0 && (lo + j < 4)) {
#pragma unroll
          for (int e = 0; e < 8; ++e) { ah0[e] = (f16)0; al0[e] = (f16)0; }
        }
        aq[0][nt] = MFMA16(ah0, bh, aq[0][nt]);
        aq[0][nt] = MFMA16(ah0, bl, aq[0][nt]);
        aq[0][nt] = MFMA16(al0, bh, aq[0][nt]);
        aq[1][nt] = MFMA16(ah1, bh, aq[1][nt]);
        aq[1][nt] = MFMA16(ah1, bl, aq[1][nt]);
        aq[1][nt] = MFMA16(al1, bh, aq[1][nt]);
      }
      wait_lgkm0();  // ds_reads sampled before next chunk's DMA lands
    }
  }

  const float SC = 0.29730177875068026f;  // 128^-0.25
#pragma unroll
  for (int nt = 0; nt < 8; ++nt) {
    const int o = o0 + nt * 16 + lo;
    const float vb = bias[o];
#pragma unroll
    for (int rt = 0; rt < 2; ++rt)
#pragma unroll
      for (int r = 0; r < 4; ++r) aq[rt][nt][r] = (aq[rt][nt][r] + vb) * SC;
  }

  if (!isK) {
    STAGE_QK(q3h, (f16)aq[rt][nt][r])
    STAGE_QK(q3l, (f16)(aq[rt][nt][r] - (float)(f16)aq[rt][nt][r]))
  } else {
    STAGE_QK(k3h, (f16)aq[rt][nt][r])
    STAGE_QK(k3l, (f16)(aq[rt][nt][r] - (float)(f16)aq[rt][nt][r]))
  }
}

// ---------------- K234: DMA-streamed scores + top-64/softmax + PV ----------
// Wave-private kbuf slots; stream loops barrier-free with per-wave fences.
// Barriers only around S-tile snapshot and P (cross-wave shared).
__global__ __launch_bounds__(512, 4) void k234_attn(
    const f16* __restrict__ q3h, const f16* __restrict__ q3l,
    const f16* __restrict__ k3h, const f16* __restrict__ k3l,
    const f16* __restrict__ v3T, f16* __restrict__ A) {
  __shared__ float Sb[16 * 516];   // 33,024 B: S fp32 half / P f16 full
  __shared__ f16 kbuf[16384];      // 32,768 B: 32 DMA slots x 512 f16
  const int tid = threadIdx.x;
  const int w = tid >> 6, lane = tid & 63;
  const int quad = lane >> 4, lo = lane & 15;
  const int qd = lane & 3, cit = lane >> 2;  // DMA lane decomposition
  const int m = blockIdx.y;
  const int r0 = blockIdx.x * 16;

  // Q fragments (A-operand) for rows r0..r0+15, all K
  const int64_t qoff = ((int64_t)m * 1024 + r0 + lo) * 128;
  f16x8 qh[4], ql[4];
#pragma unroll
  for (int kk = 0; kk < 4; ++kk) {
    qh[kk] = ldfrag(q3h + qoff + kk * 32 + quad * 8);
    ql[kk] = ldfrag(q3l + qoff + kk * 32 + quad * 8);
  }

  unsigned key[2][16];
  unsigned kmn0 = 0xFFFFFFFFu, kmn1 = 0xFFFFFFFFu;

  // ---- phase 1: S = Q @ K^T, streamed; wave w owns col-tile w per chunk ---
#pragma unroll
  for (int half = 0; half < 2; ++half) {
    f32x4 acc[4];
#pragma unroll
    for (int i = 0; i < 4; ++i)
#pragma unroll
      for (int r = 0; r < 4; ++r) acc[i][r] = 0.f;

    for (int kp = 0; kp < 2; ++kp) {      // 64-K span (full 128B lines)
#pragma unroll
      for (int cc = 0; cc < 4; ++cc) {    // 128-col chunk
        const int c0 = half * 512 + cc * 128;
        const int64_t rowg = (int64_t)(m * 1024 + c0 + w * 16 + cit) * 128;
#pragma unroll
        for (int t = 0; t < 2; ++t) {
          const f16* srcb = t ? k3l : k3h;
#pragma unroll
          for (int kkh = 0; kkh < 2; ++kkh)
            dma16(srcb + rowg + (kp * 2 + kkh) * 32 + qd * 8,
                  kbuf + (w * 4 + t * 2 + kkh) * 512);
        }
        wait_vm0();   // own DMA landed (slots are wave-private)
#pragma unroll
        for (int kkh = 0; kkh < 2; ++kkh) {
          const int kkg = kp * 2 + kkh;
          f16x8 bh = *(const f16x8*)(kbuf + (w * 4 + kkh) * 512 +
                                     (lo * 4 + quad) * 8);
          f16x8 bl = *(const f16x8*)(kbuf + (w * 4 + 2 + kkh) * 512 +
                                     (lo * 4 + quad) * 8);
          acc[cc] = MFMA16(qh[kkg], bh, acc[cc]);
          acc[cc] = MFMA16(qh[kkg], bl, acc[cc]);
          acc[cc] = MFMA16(ql[kkg], bh, acc[cc]);
        }
        wait_lgkm0();  // reads sampled before next chunk's DMA lands
      }
    }
    // write S half (cols half*512 .. +511)
#pragma unroll
    for (int cc = 0; cc < 4; ++cc)
#pragma unroll
      for (int r = 0; r < 4; ++r)
        Sb[(quad * 4 + r) * 516 + cc * 128 + w * 16 + lo] = acc[cc][r];
    __syncthreads();   // cross-wave: snapshot reads other waves' columns
    // snapshot keys: wave w owns rows 2w, 2w+1
#pragma unroll
    for (int rr = 0; rr < 2; ++rr) {
      const float4* rp = (const float4*)(Sb + (w * 2 + rr) * 516);
#pragma unroll
      for (int i2 = 0; i2 < 2; ++i2) {
        const float4 f4 = rp[i2 * 64 + lane];
        const float fe[4] = {f4.x, f4.y, f4.z, f4.w};
#pragma unroll
        for (int e = 0; e < 4; ++e) {
          const unsigned u = __builtin_bit_cast(unsigned, fe[e]);
          const unsigned k = (u & 0x80000000u) ? ~u : (u | 0x80000000u);
          key[rr][half * 8 + i2 * 4 + e] = k;
          if (rr == 0) kmn0 = min(kmn0, k); else kmn1 = min(kmn1, k);
        }
      }
    }
    __syncthreads();  // all key reads done before next half overwrites S
  }

  // ---- phase 2: exact fp32 top-64 + rowmin + causal + softmax -> P --------
  f16* P16 = (f16*)Sb;  // row stride 1032 f16 (= 516 f32)
  {
#pragma unroll
    for (int off = 32; off; off >>= 1) {
      kmn0 = min(kmn0, (unsigned)__shfl_xor((int)kmn0, off));
      kmn1 = min(kmn1, (unsigned)__shfl_xor((int)kmn1, off));
    }
    unsigned th0 = 0u, th1 = 0u;
    for (int b = 31; b >= 0; --b) {
      const unsigned c0 = th0 | (1u << b);
      const unsigned c1 = th1 | (1u << b);
      int cnt0 = 0, cnt1 = 0;
#pragma unroll
      for (int i = 0; i < 16; ++i) {
        cnt0 += (int)__popcll(__ballot(key[0][i] >= c0));
        cnt1 += (int)__popcll(__ballot(key[1][i] >= c1));
      }
      if (cnt0 >= 64) th0 = c0;
      if (cnt1 >= 64) th1 = c1;
    }

#pragma unroll
    for (int rr = 0; rr < 2; ++rr) {
      const unsigned kth = rr ? th1 : th0;
      const unsigned kmn = rr ? kmn1 : kmn0;
      const int row = w * 2 + rr, t2 = r0 + row;
      const unsigned umn = (kmn & 0x80000000u) ? (kmn ^ 0x80000000u) : ~kmn;
      const float mn = __builtin_bit_cast(float, umn);   // exact row min
      const unsigned ukv = (kth & 0x80000000u) ? (kth ^ 0x80000000u) : ~kth;
      const float kv = __builtin_bit_cast(float, ukv);   // 64th-largest value

      float ev[16];
      float sum = 0.f;
#pragma unroll
      for (int j = 0; j < 16; ++j) {
        const int s = (j >> 3) * 512 + ((j >> 2) & 1) * 256 + lane * 4 + (j & 3);
        const unsigned k = key[rr][j];
        const unsigned uu = (k & 0x80000000u) ? (k ^ 0x80000000u) : ~k;
        const float f = __builtin_bit_cast(float, uu);
        const float ww = (k >= kth) ? f : mn;
        const float x = (s <= t2) ? __expf(ww - kv) : 0.f;  // kv-stabilized
        ev[j] = x;
        sum += x;
      }
      for (int off = 32; off; off >>= 1) sum += __shfl_xor(sum, off);
      const float inv = 1.0f / sum;

      f16* prow = P16 + row * 1032;  // in place over this row's S
#pragma unroll
      for (int hh = 0; hh < 2; ++hh)
#pragma unroll
        for (int i2 = 0; i2 < 2; ++i2) {
          f16x4 pk;
#pragma unroll
          for (int e = 0; e < 4; ++e)
            pk[e] = (f16)(ev[hh * 8 + i2 * 4 + e] * inv);
          *(f16x4*)(prow + hh * 512 + i2 * 256 + lane * 4) = pk;
        }
    }
  }
  __syncthreads();  // P visible to all waves

  // ---- phase 3: A = P @ V, streamed barrier-free; wave w -> kc w*16..+15 --
  {
    f32x4 oacc;
#pragma unroll
    for (int r = 0; r < 4; ++r) oacc[r] = 0.f;
    const int64_t vrow = (int64_t)(m * 128 + w * 16 + cit) * 1024;
    for (int kb = 0; kb < 16; ++kb) {   // 64-K spans
#pragma unroll
      for (int kkh = 0; kkh < 2; ++kkh)
        dma16(v3T + vrow + kb * 64 + kkh * 32 + qd * 8,
              kbuf + (w * 2 + kkh) * 512);
      wait_vm0();
#pragma unroll
      for (int kkh = 0; kkh < 2; ++kkh) {
        f16x8 vf = *(const f16x8*)(kbuf + (w * 2 + kkh) * 512 +
                                   (lo * 4 + quad) * 8);
        f16x8 af = *(const f16x8*)(P16 + lo * 1032 + kb * 64 + kkh * 32 +
                                   quad * 8);
        oacc = MFMA16(af, vf, oacc);
      }
      wait_lgkm0();
    }
#pragma unroll
    for (int r = 0; r < 4; ++r)
      A[((int64_t)m * 1024 + r0 + quad * 4 + r) * 128 + w * 16 + lo] =
          (f16)oacc[r];
  }
}

// ---------------- K5: gather + output projection + bias --------------------
__global__ __launch_bounds__(256) void k5_proj(
    const f16* __restrict__ A, const f16* __restrict__ Wub,
    const float* __restrict__ bu, float* __restrict__ out) {
  const int w = threadIdx.x >> 6, lane = threadIdx.x & 63;
  const int quad = lane >> 4, lo = lane & 15;
  const int rt = w & 1, ch = w >> 1;
  const int r0 = blockIdx.x * 32 + rt * 16;  // row in [0,8192) = b*1024 + t2
  const int r = r0 + lo;
  const int bI = r >> 10, t2 = r & 1023;

  f32x4 acc[4];
#pragma unroll
  for (int i = 0; i < 4; ++i)
#pragma unroll
    for (int rr = 0; rr < 4; ++rr) acc[i][rr] = 0.f;

#pragma unroll 2
  for (int kk = 0; kk < 32; ++kk) {
    const int o = kk * 32 + quad * 8;  // feature index 0..1023
    const int j = o >> 7, kc = o & 127;
    f16x8 a = ldfrag(A + (((int64_t)(bI * 8 + j) * 1024 + t2) * 128 + kc));
    f16x8 wb[4];
#pragma unroll
    for (int nt = 0; nt < 4; ++nt)
      wb[nt] = ldfrag(Wub + (int64_t)(ch * 64 + nt * 16 + lo) * 1024 + o);
#pragma unroll
    for (int nt = 0; nt < 4; ++nt) acc[nt] = MFMA16(a, wb[nt], acc[nt]);
  }
#pragma unroll
  for (int nt = 0; nt < 4; ++nt) {
    const int col = ch * 64 + nt * 16 + lo;
    const float bias = bu[col];
#pragma unroll
    for (int rr = 0; rr < 4; ++rr) {
      const int row = r0 + quad * 4 + rr;
      out[(int64_t)row * 128 + col] = acc[nt][rr] + bias;
    }
  }
}

// ---------------- launcher --------------------------------------------------
extern "C" void kernel_launch(void* const* d_in, const int* in_sizes, int n_in,
                              void* d_out, int out_size, void* d_ws, size_t ws_size,
                              hipStream_t stream) {
  const float* x  = (const float*)d_in[0];
  const float* Wq = (const float*)d_in[1];
  const float* bq = (const float*)d_in[2];
  const float* Wk = (const float*)d_in[3];
  const float* bk = (const float*)d_in[4];
  const float* Wv = (const float*)d_in[5];
  const float* bv = (const float*)d_in[6];
  const float* Wu = (const float*)d_in[7];
  const float* bu = (const float*)d_in[8];
  float* out = (float*)d_out;

  char* ws = (char*)d_ws;
  f16* xh  = (f16*)ws;  ws += 2097152;
  f16* xl  = (f16*)ws;  ws += 2097152;
  f16* Wqh = (f16*)ws;  ws += 1310720;
  f16* Wql = (f16*)ws;  ws += 1310720;
  f16* Wkh = (f16*)ws;  ws += 1310720;
  f16* Wkl = (f16*)ws;  ws += 1310720;
  f16* Wvb = (f16*)ws;  ws += 262144;
  f16* Wub = (f16*)ws;  ws += 262144;
  f16* q3h = (f16*)ws;  ws += 16777216;           // 64*1024*128 fp16
  f16* q3l = (f16*)ws;  ws += 16777216;
  f16* k3h = (f16*)ws;  ws += 16777216;
  f16* k3l = (f16*)ws;  ws += 16777216;
  f16* v3T = (f16*)ws;  ws += 16777216;
  f16* A   = (f16*)ws;  ws += 16777216;           // total ~105.5 MB

  // K0: repack (exactly 2621440 threads = 10240 * 256)
  k0_prep<<<10240, 256, 0, stream>>>(x, Wq, Wk, Wv, Wu,
                                     xh, xl, Wqh, Wql, Wkh, Wkl, Wvb, Wub);

  // K1: convs + scramble; DMA-streamed weights, barrier-free waves
  k1_conv<<<dim3(256, 2, 2), 256, 0, stream>>>(xh, xl, Wqh, Wql, Wkh, Wkl, Wvb,
                                               bq, bk, bv, q3h, q3l, k3h, k3l,
                                               v3T);

  // K234: DMA-streamed fused attention, barrier-free streams
  k234_attn<<<dim3(64, 64), 512, 0, stream>>>(q3h, q3l, k3h, k3l, v3T, A);

  // K5: projection (8192 rows / 32 per block)
  k5_proj<<<256, 256, 0, stream>>>(A, Wub, bu, out);

  (void)in_sizes; (void)n_in; (void)out_size; (void)ws_size;
}